// Round 2
// baseline (2520.061 us; speedup 1.0000x reference)
//
#include <hip/hip_runtime.h>

#define N_NODES 100000
#define N_EDGES 1600000
#define HID 128
#define NBUCK 196  // ceil(N_NODES / 512)

// ---------------- CSR build ----------------

// Per-row degree + per-bucket (row>>9) count in one pass.
__global__ void k_hist2(const int* __restrict__ row, int* __restrict__ deg,
                        int* __restrict__ bcnt) {
    int e = blockIdx.x * blockDim.x + threadIdx.x;
    if (e < N_EDGES) {
        int r = row[e];
        atomicAdd(&deg[r], 1);
        atomicAdd(&bcnt[r >> 9], 1);
    }
}

// Exclusive scan of 196 bucket counts -> bucket cursors (single block).
__global__ void k_scanB(const int* __restrict__ bcnt, int* __restrict__ bcur) {
    __shared__ int s[256];
    int t = threadIdx.x;
    int v = (t < NBUCK) ? bcnt[t] : 0;
    s[t] = v;
    __syncthreads();
    for (int off = 1; off < 256; off <<= 1) {
        int x = (t >= off) ? s[t - off] : 0;
        __syncthreads();
        s[t] += x;
        __syncthreads();
    }
    if (t < NBUCK) bcur[t] = s[t] - v;
}

// Per-block exclusive scan of deg (Hillis-Steele in LDS), block sums out.
__global__ void k_scan1(const int* __restrict__ deg, int* __restrict__ excl,
                        int* __restrict__ bsum) {
    __shared__ int s[256];
    int t = threadIdx.x;
    int i = blockIdx.x * 256 + t;
    int v = (i < N_NODES) ? deg[i] : 0;
    s[t] = v;
    __syncthreads();
    for (int off = 1; off < 256; off <<= 1) {
        int x = (t >= off) ? s[t - off] : 0;
        __syncthreads();
        s[t] += x;
        __syncthreads();
    }
    if (i < N_NODES) excl[i] = s[t] - v;
    if (t == 255) bsum[blockIdx.x] = s[255];
}

__global__ void k_scan2(int* __restrict__ bsum, int nb) {
    __shared__ int s[512];
    int t = threadIdx.x;
    int v = (t < nb) ? bsum[t] : 0;
    s[t] = v;
    __syncthreads();
    for (int off = 1; off < 512; off <<= 1) {
        int x = (t >= off) ? s[t - off] : 0;
        __syncthreads();
        s[t] += x;
        __syncthreads();
    }
    if (t < nb) bsum[t] = s[t] - v;
}

__global__ void k_scan3(int* __restrict__ row_ptr, const int* __restrict__ bsum,
                        int* __restrict__ nxt) {
    int i = blockIdx.x * 256 + threadIdx.x;
    if (i < N_NODES) {
        int v = row_ptr[i] + bsum[blockIdx.x];
        row_ptr[i] = v;
        nxt[i] = v;
    }
    if (i == 0) row_ptr[N_NODES] = N_EDGES;
}

// Pass 1: bin edges by bucket. Destinations are 196 advancing cursors ->
// each 64B line is filled by consecutive 16B stores before moving on.
__global__ void k_pass1(const int* __restrict__ row, const int* __restrict__ col,
                        const float* __restrict__ vals, int* __restrict__ bcur,
                        int4* __restrict__ eb) {
    int e = blockIdx.x * blockDim.x + threadIdx.x;
    if (e < N_EDGES) {
        int r = row[e];
        int p = atomicAdd(&bcur[r >> 9], 1);
        eb[p] = make_int4(r, col[e], __float_as_int(vals[e]), 0);
    }
}

// Pass 2: contiguous read of bucket-grouped edges; scatter (col,val) into the
// final CSR slot. Consecutive sources share a bucket -> destinations confined
// to that bucket's ~64KB CSR window -> L2-local.
__global__ void k_pass2(const int4* __restrict__ eb, int* __restrict__ nxt,
                        int2* __restrict__ evf) {
    int i = blockIdx.x * blockDim.x + threadIdx.x;
    if (i < N_EDGES) {
        int4 t = eb[i];
        int q = atomicAdd(&nxt[t.x], 1);
        evf[q] = make_int2(t.y, t.z);
    }
}

// ---------------- GEMM1: H = relu(X @ W_in + b_in) ----------------
// 256 threads, 64-row x 128-col tile, no LDS: per-thread 8 rows x 4 cols.
// X loads are wave-broadcast (address uniform over tx); W loads coalesced.
template <bool GUARD>
__device__ __forceinline__ void gemm_in_body(const float* __restrict__ X,
                                             const float* __restrict__ W,
                                             const float* __restrict__ b,
                                             float* __restrict__ H, int r0, int tid) {
    int tx = tid & 31, ty = tid >> 5;
    int rbase = r0 + ty * 8;
    const float4* W4 = (const float4*)W;
    const float4* Xg = (const float4*)X;
    float4 acc[8];
#pragma unroll
    for (int i = 0; i < 8; i++) acc[i] = make_float4(0.f, 0.f, 0.f, 0.f);

    for (int k4 = 0; k4 < 32; k4++) {
        float4 w[4];
#pragma unroll
        for (int kk = 0; kk < 4; kk++) w[kk] = W4[(k4 * 4 + kk) * 32 + tx];
#pragma unroll
        for (int i = 0; i < 8; i++) {
            float4 x = make_float4(0.f, 0.f, 0.f, 0.f);
            if (!GUARD || rbase + i < N_NODES) x = Xg[(size_t)(rbase + i) * 32 + k4];
            acc[i].x += x.x * w[0].x + x.y * w[1].x + x.z * w[2].x + x.w * w[3].x;
            acc[i].y += x.x * w[0].y + x.y * w[1].y + x.z * w[2].y + x.w * w[3].y;
            acc[i].z += x.x * w[0].z + x.y * w[1].z + x.z * w[2].z + x.w * w[3].z;
            acc[i].w += x.x * w[0].w + x.y * w[1].w + x.z * w[2].w + x.w * w[3].w;
        }
    }

    float4 bb = ((const float4*)b)[tx];
#pragma unroll
    for (int i = 0; i < 8; i++) {
        if (!GUARD || rbase + i < N_NODES) {
            float4 h;
            h.x = fmaxf(acc[i].x + bb.x, 0.f);
            h.y = fmaxf(acc[i].y + bb.y, 0.f);
            h.z = fmaxf(acc[i].z + bb.z, 0.f);
            h.w = fmaxf(acc[i].w + bb.w, 0.f);
            ((float4*)H)[(size_t)(rbase + i) * 32 + tx] = h;
        }
    }
}

__global__ __launch_bounds__(256) void k_gemm_in(const float* __restrict__ X,
                                                 const float* __restrict__ W,
                                                 const float* __restrict__ b,
                                                 float* __restrict__ H) {
    int r0 = blockIdx.x * 64;
    if (r0 + 64 <= N_NODES)
        gemm_in_body<false>(X, W, b, H, r0, threadIdx.x);
    else
        gemm_in_body<true>(X, W, b, H, r0, threadIdx.x);
}

// ---------------- SpMM: one wave per row, register accumulate ----------------
__global__ __launch_bounds__(256) void k_spmm(const int* __restrict__ row_ptr,
                                              const int2* __restrict__ evf,
                                              const float* __restrict__ Hin,
                                              float* __restrict__ Hout) {
    int wid = (blockIdx.x * blockDim.x + threadIdx.x) >> 6;
    int lane = threadIdx.x & 63;
    if (wid >= N_NODES) return;
    int s = __builtin_amdgcn_readfirstlane(row_ptr[wid]);
    int e = __builtin_amdgcn_readfirstlane(row_ptr[wid + 1]);
    const float2* H2 = (const float2*)Hin;
    float2 acc = make_float2(0.f, 0.f);
    int j = s;
    for (; j + 1 < e; j += 2) {
        int2 e0 = evf[j];
        int2 e1 = evf[j + 1];
        float2 h0 = H2[(size_t)e0.x * 64 + lane];
        float2 h1 = H2[(size_t)e1.x * 64 + lane];
        float v0 = __int_as_float(e0.y);
        float v1 = __int_as_float(e1.y);
        acc.x += v0 * h0.x + v1 * h1.x;
        acc.y += v0 * h0.y + v1 * h1.y;
    }
    if (j < e) {
        int2 e0 = evf[j];
        float2 h0 = H2[(size_t)e0.x * 64 + lane];
        float v0 = __int_as_float(e0.y);
        acc.x += v0 * h0.x;
        acc.y += v0 * h0.y;
    }
    ((float2*)Hout)[(size_t)wid * 64 + lane] = acc;
}

// ------- Final: out = relu(AH@W1 + A2H@W2) @ W_out + b_out (fused) -------
template <bool GUARD>
__device__ __forceinline__ void gemm_out_body(const float* __restrict__ AH,
                                              const float* __restrict__ A2H,
                                              const float* __restrict__ W1,
                                              const float* __restrict__ W2,
                                              const float* __restrict__ Wout,
                                              const float* __restrict__ bout,
                                              float* __restrict__ out, int r0, int tid) {
    int tx = tid & 31, ty = tid >> 5;
    int rbase = r0 + ty * 8;
    const float4* W14 = (const float4*)W1;
    const float4* W24 = (const float4*)W2;
    const float4* Ag = (const float4*)AH;
    const float4* Bg = (const float4*)A2H;
    float4 acc[8];
#pragma unroll
    for (int i = 0; i < 8; i++) acc[i] = make_float4(0.f, 0.f, 0.f, 0.f);

    for (int k4 = 0; k4 < 32; k4++) {
        float4 w1[4], w2[4];
#pragma unroll
        for (int kk = 0; kk < 4; kk++) {
            w1[kk] = W14[(k4 * 4 + kk) * 32 + tx];
            w2[kk] = W24[(k4 * 4 + kk) * 32 + tx];
        }
#pragma unroll
        for (int i = 0; i < 8; i++) {
            float4 a = make_float4(0.f, 0.f, 0.f, 0.f);
            float4 bv = make_float4(0.f, 0.f, 0.f, 0.f);
            if (!GUARD || rbase + i < N_NODES) {
                a = Ag[(size_t)(rbase + i) * 32 + k4];
                bv = Bg[(size_t)(rbase + i) * 32 + k4];
            }
            acc[i].x += a.x * w1[0].x + a.y * w1[1].x + a.z * w1[2].x + a.w * w1[3].x
                      + bv.x * w2[0].x + bv.y * w2[1].x + bv.z * w2[2].x + bv.w * w2[3].x;
            acc[i].y += a.x * w1[0].y + a.y * w1[1].y + a.z * w1[2].y + a.w * w1[3].y
                      + bv.x * w2[0].y + bv.y * w2[1].y + bv.z * w2[2].y + bv.w * w2[3].y;
            acc[i].z += a.x * w1[0].z + a.y * w1[1].z + a.z * w1[2].z + a.w * w1[3].z
                      + bv.x * w2[0].z + bv.y * w2[1].z + bv.z * w2[2].z + bv.w * w2[3].z;
            acc[i].w += a.x * w1[0].w + a.y * w1[1].w + a.z * w1[2].w + a.w * w1[3].w
                      + bv.x * w2[0].w + bv.y * w2[1].w + bv.z * w2[2].w + bv.w * w2[3].w;
        }
    }

    float4 wo = ((const float4*)Wout)[tx];
    float bo = bout[0];
    float partial[8];
#pragma unroll
    for (int i = 0; i < 8; i++) {
        float hx = fmaxf(acc[i].x, 0.f);
        float hy = fmaxf(acc[i].y, 0.f);
        float hz = fmaxf(acc[i].z, 0.f);
        float hw = fmaxf(acc[i].w, 0.f);
        partial[i] = hx * wo.x + hy * wo.y + hz * wo.z + hw * wo.w;
    }
#pragma unroll
    for (int off = 1; off < 32; off <<= 1) {
#pragma unroll
        for (int i = 0; i < 8; i++) partial[i] += __shfl_xor(partial[i], off, 64);
    }
    if (tx == 0) {
#pragma unroll
        for (int i = 0; i < 8; i++) {
            if (!GUARD || rbase + i < N_NODES) out[rbase + i] = partial[i] + bo;
        }
    }
}

__global__ __launch_bounds__(256) void k_gemm_out(const float* __restrict__ AH,
                                                  const float* __restrict__ A2H,
                                                  const float* __restrict__ W1,
                                                  const float* __restrict__ W2,
                                                  const float* __restrict__ Wout,
                                                  const float* __restrict__ bout,
                                                  float* __restrict__ out) {
    int r0 = blockIdx.x * 64;
    if (r0 + 64 <= N_NODES)
        gemm_out_body<false>(AH, A2H, W1, W2, Wout, bout, out, r0, threadIdx.x);
    else
        gemm_out_body<true>(AH, A2H, W1, W2, Wout, bout, out, r0, threadIdx.x);
}

// ---------------- launch ----------------

extern "C" void kernel_launch(void* const* d_in, const int* in_sizes, int n_in,
                              void* d_out, int out_size, void* d_ws, size_t ws_size,
                              hipStream_t stream) {
    const float* X    = (const float*)d_in[0];
    const int*   row  = (const int*)d_in[1];
    const int*   col  = (const int*)d_in[2];
    const float* vals = (const float*)d_in[3];
    const float* W_in = (const float*)d_in[4];
    const float* b_in = (const float*)d_in[5];
    const float* W1   = (const float*)d_in[6];
    const float* W2   = (const float*)d_in[7];
    const float* Wout = (const float*)d_in[8];
    const float* bout = (const float*)d_in[9];
    float* out = (float*)d_out;

    char* ws = (char*)d_ws;
    size_t off = 0;
    auto alloc = [&](size_t bytes) -> void* {
        void* p = ws + off;
        off += (bytes + 511) & ~(size_t)511;
        return p;
    };
    float* B0      = (float*)alloc((size_t)N_NODES * HID * 4);  // H, then A2H
    float* B1      = (float*)alloc((size_t)N_NODES * HID * 4);  // AH
    int*   deg     = (int*)alloc((size_t)N_NODES * 4);
    int*   row_ptr = (int*)alloc((size_t)(N_NODES + 1) * 4);
    int*   nxt     = (int*)alloc((size_t)N_NODES * 4);
    int*   bsum    = (int*)alloc(512 * 4);
    int*   bcnt    = (int*)alloc(NBUCK * 4);
    int*   bcur    = (int*)alloc(NBUCK * 4);
    int2*  evf     = (int2*)alloc((size_t)N_EDGES * 8);
    // eb (25.6MB) aliases B0 (51.2MB): eb is dead before k_gemm_in writes B0.
    int4*  eb      = (int4*)B0;

    hipMemsetAsync(deg, 0, (size_t)N_NODES * 4, stream);
    hipMemsetAsync(bcnt, 0, NBUCK * 4, stream);

    int eblk = (N_EDGES + 255) / 256;
    int nb = (N_NODES + 255) / 256;  // 391
    k_hist2<<<eblk, 256, 0, stream>>>(row, deg, bcnt);
    k_scanB<<<1, 256, 0, stream>>>(bcnt, bcur);
    k_pass1<<<eblk, 256, 0, stream>>>(row, col, vals, bcur, eb);
    k_scan1<<<nb, 256, 0, stream>>>(deg, row_ptr, bsum);
    k_scan2<<<1, 512, 0, stream>>>(bsum, nb);
    k_scan3<<<nb, 256, 0, stream>>>(row_ptr, bsum, nxt);
    k_pass2<<<eblk, 256, 0, stream>>>(eb, nxt, evf);

    int gblk = (N_NODES + 63) / 64;  // 1563
    k_gemm_in<<<gblk, 256, 0, stream>>>(X, W_in, b_in, B0);

    int sblk = (N_NODES + 3) / 4;  // 4 rows (waves) per block
    k_spmm<<<sblk, 256, 0, stream>>>(row_ptr, evf, B0, B1);  // AH = A*H
    k_spmm<<<sblk, 256, 0, stream>>>(row_ptr, evf, B1, B0);  // A2H = A*AH

    k_gemm_out<<<gblk, 256, 0, stream>>>(B1, B0, W1, W2, Wout, bout, out);
}

// Round 3
// 532.651 us; speedup vs baseline: 4.7312x; 4.7312x over previous
//
#include <hip/hip_runtime.h>

#define N_NODES 100000
#define N_EDGES 1600000

typedef float f32x4 __attribute__((ext_vector_type(4)));
typedef short bf16x8 __attribute__((ext_vector_type(8)));

// fp32 -> bf16 round-to-nearest-even, returns bits in low 16.
__device__ __forceinline__ unsigned f2bf_bits(float f) {
    unsigned u = __float_as_uint(f);
    u += 0x7fffu + ((u >> 16) & 1u);
    return u >> 16;
}
__device__ __forceinline__ float bf_lo(unsigned u) { return __uint_as_float(u << 16); }
__device__ __forceinline__ float bf_hi(unsigned u) { return __uint_as_float(u & 0xffff0000u); }

__device__ __forceinline__ bf16x8 pack_bf8(float4 a, float4 b) {
    bf16x8 r;
    r[0] = (short)f2bf_bits(a.x); r[1] = (short)f2bf_bits(a.y);
    r[2] = (short)f2bf_bits(a.z); r[3] = (short)f2bf_bits(a.w);
    r[4] = (short)f2bf_bits(b.x); r[5] = (short)f2bf_bits(b.y);
    r[6] = (short)f2bf_bits(b.z); r[7] = (short)f2bf_bits(b.w);
    return r;
}

// ---------------- CSR build (round-1 proven path; 100K-way atomics only) ----

__global__ void k_hist(const int* __restrict__ row, int* __restrict__ deg) {
    int e = blockIdx.x * blockDim.x + threadIdx.x;
    if (e < N_EDGES) atomicAdd(&deg[row[e]], 1);
}

__global__ void k_scan1(const int* __restrict__ deg, int* __restrict__ excl,
                        int* __restrict__ bsum) {
    __shared__ int s[256];
    int t = threadIdx.x;
    int i = blockIdx.x * 256 + t;
    int v = (i < N_NODES) ? deg[i] : 0;
    s[t] = v;
    __syncthreads();
    for (int off = 1; off < 256; off <<= 1) {
        int x = (t >= off) ? s[t - off] : 0;
        __syncthreads();
        s[t] += x;
        __syncthreads();
    }
    if (i < N_NODES) excl[i] = s[t] - v;
    if (t == 255) bsum[blockIdx.x] = s[255];
}

__global__ void k_scan2(int* __restrict__ bsum, int nb) {
    __shared__ int s[512];
    int t = threadIdx.x;
    int v = (t < nb) ? bsum[t] : 0;
    s[t] = v;
    __syncthreads();
    for (int off = 1; off < 512; off <<= 1) {
        int x = (t >= off) ? s[t - off] : 0;
        __syncthreads();
        s[t] += x;
        __syncthreads();
    }
    if (t < nb) bsum[t] = s[t] - v;
}

__global__ void k_scan3(int* __restrict__ row_ptr, const int* __restrict__ bsum,
                        int* __restrict__ nxt) {
    int i = blockIdx.x * 256 + threadIdx.x;
    if (i < N_NODES) {
        int v = row_ptr[i] + bsum[blockIdx.x];
        row_ptr[i] = v;
        nxt[i] = v;
    }
    if (i == 0) row_ptr[N_NODES] = N_EDGES;
}

// Single 8B store per edge (vs round-1's two 4B stores): halves write amp.
__global__ void k_scatter(const int* __restrict__ row, const int* __restrict__ col,
                          const float* __restrict__ vals, int* __restrict__ nxt,
                          int2* __restrict__ evf) {
    int e = blockIdx.x * blockDim.x + threadIdx.x;
    if (e < N_EDGES) {
        int p = atomicAdd(&nxt[row[e]], 1);
        evf[p] = make_int2(col[e], __float_as_int(vals[e]));
    }
}

// ---------------- weight convert+transpose: Wt[n][k] = bf16(W[k][n]) -------

__global__ void k_cvtw(const float* __restrict__ W, short* __restrict__ Wt) {
    int t = blockIdx.x * 256 + threadIdx.x;
    if (t < 128 * 128) {
        int n = t & 127, k = t >> 7;
        Wt[n * 128 + k] = (short)f2bf_bits(W[k * 128 + n]);
    }
}

// ---------------- GEMM1: H(bf16) = relu(X @ W_in + b_in), MFMA -------------
// Block = 4 waves, each wave 16 rows x 128 cols. 16x16x32 bf16 MFMA.
// A-frag: A[m=lane&15][k=quad*8+j]; D: [row=quad*4+r][col=lane&15].
__global__ __launch_bounds__(256) void k_gemm_in(const float* __restrict__ X,
                                                 const short* __restrict__ Wt,
                                                 const float* __restrict__ b,
                                                 unsigned short* __restrict__ H) {
    __shared__ unsigned short st[4][16 * 128];
    int lane = threadIdx.x & 63, wv = threadIdx.x >> 6;
    int quad = lane >> 4, c16 = lane & 15;
    int rbase = blockIdx.x * 64 + wv * 16;
    int arow = rbase + c16;
    bool aok = arow < N_NODES;
    const float4* Xg = (const float4*)X;

    f32x4 acc[8] = {};
#pragma unroll
    for (int kc = 0; kc < 4; kc++) {
        float4 f0 = make_float4(0.f, 0.f, 0.f, 0.f), f1 = f0;
        if (aok) {
            f0 = Xg[(size_t)arow * 32 + kc * 8 + quad * 2];
            f1 = Xg[(size_t)arow * 32 + kc * 8 + quad * 2 + 1];
        }
        bf16x8 af = pack_bf8(f0, f1);
#pragma unroll
        for (int n = 0; n < 8; n++) {
            bf16x8 bf = *(const bf16x8*)&Wt[(n * 16 + c16) * 128 + kc * 32 + quad * 8];
            acc[n] = __builtin_amdgcn_mfma_f32_16x16x32_bf16(af, bf, acc[n], 0, 0, 0);
        }
    }

    // epilogue: bias + relu -> bf16 -> LDS (layout shuffle) -> coalesced store
#pragma unroll
    for (int n = 0; n < 8; n++) {
        float bb = b[n * 16 + c16];
#pragma unroll
        for (int r = 0; r < 4; r++) {
            float v = fmaxf(acc[n][r] + bb, 0.f);
            st[wv][(quad * 4 + r) * 128 + n * 16 + c16] = (unsigned short)f2bf_bits(v);
        }
    }
    __syncthreads();
    int t = threadIdx.x;
    int lrow = t >> 2;                 // 0..63
    int orow = blockIdx.x * 64 + lrow;
    if (orow < N_NODES) {
        const int4* src = (const int4*)&st[lrow >> 4][(lrow & 15) * 128 + (t & 3) * 32];
        int4* dst = (int4*)&H[(size_t)orow * 128 + (t & 3) * 32];
        dst[0] = src[0]; dst[1] = src[1]; dst[2] = src[2]; dst[3] = src[3];
    }
}

// ---------------- SpMM: wave per row, bf16 gather, fp32 accumulate ---------
template <int OUTF32>
__global__ __launch_bounds__(256) void k_spmm_t(const int* __restrict__ rp,
                                                const int2* __restrict__ evf,
                                                const unsigned* __restrict__ Hin,
                                                unsigned* __restrict__ HoB,
                                                float2* __restrict__ HoF) {
    int wid = (blockIdx.x * blockDim.x + threadIdx.x) >> 6;
    int lane = threadIdx.x & 63;
    if (wid >= N_NODES) return;
    int s = __builtin_amdgcn_readfirstlane(rp[wid]);
    int e = __builtin_amdgcn_readfirstlane(rp[wid + 1]);
    float ax = 0.f, ay = 0.f;
    int j = s;
    for (; j + 1 < e; j += 2) {
        int2 e0 = evf[j];
        int2 e1 = evf[j + 1];
        unsigned u0 = Hin[(size_t)e0.x * 64 + lane];
        unsigned u1 = Hin[(size_t)e1.x * 64 + lane];
        float v0 = __int_as_float(e0.y), v1 = __int_as_float(e1.y);
        ax += v0 * bf_lo(u0) + v1 * bf_lo(u1);
        ay += v0 * bf_hi(u0) + v1 * bf_hi(u1);
    }
    if (j < e) {
        int2 e0 = evf[j];
        unsigned u0 = Hin[(size_t)e0.x * 64 + lane];
        float v0 = __int_as_float(e0.y);
        ax += v0 * bf_lo(u0);
        ay += v0 * bf_hi(u0);
    }
    if (OUTF32) {
        HoF[(size_t)wid * 64 + lane] = make_float2(ax, ay);
    } else {
        HoB[(size_t)wid * 64 + lane] = (f2bf_bits(ay) << 16) | f2bf_bits(ax);
    }
}

// ------- Final: out = relu(AH@W1 + A2H@W2) @ W_out + b_out, MFMA fused -----
// AH read as bf16 directly; A2H read fp32 -> cvt (keeps error chain short).
__global__ __launch_bounds__(256) void k_gemm_out(const unsigned short* __restrict__ AH,
                                                  const float* __restrict__ A2H,
                                                  const short* __restrict__ Wt1,
                                                  const short* __restrict__ Wt2,
                                                  const float* __restrict__ Wout,
                                                  const float* __restrict__ bout,
                                                  float* __restrict__ out) {
    int lane = threadIdx.x & 63, wv = threadIdx.x >> 6;
    int quad = lane >> 4, c16 = lane & 15;
    int rbase = blockIdx.x * 64 + wv * 16;
    int arow = rbase + c16;
    bool aok = arow < N_NODES;
    const float4* A2g = (const float4*)A2H;

    f32x4 acc[8] = {};
#pragma unroll
    for (int kc = 0; kc < 4; kc++) {
        bf16x8 afA = {};
        float4 f0 = make_float4(0.f, 0.f, 0.f, 0.f), f1 = f0;
        if (aok) {
            afA = *(const bf16x8*)&AH[(size_t)arow * 128 + kc * 32 + quad * 8];
            f0 = A2g[(size_t)arow * 32 + kc * 8 + quad * 2];
            f1 = A2g[(size_t)arow * 32 + kc * 8 + quad * 2 + 1];
        }
        bf16x8 afB = pack_bf8(f0, f1);
#pragma unroll
        for (int n = 0; n < 8; n++) {
            bf16x8 b1 = *(const bf16x8*)&Wt1[(n * 16 + c16) * 128 + kc * 32 + quad * 8];
            bf16x8 b2 = *(const bf16x8*)&Wt2[(n * 16 + c16) * 128 + kc * 32 + quad * 8];
            acc[n] = __builtin_amdgcn_mfma_f32_16x16x32_bf16(afA, b1, acc[n], 0, 0, 0);
            acc[n] = __builtin_amdgcn_mfma_f32_16x16x32_bf16(afB, b2, acc[n], 0, 0, 0);
        }
    }

    // fused epilogue: relu -> dot with Wout -> reduce over the 16 col-lanes
    float part[4] = {0.f, 0.f, 0.f, 0.f};
#pragma unroll
    for (int n = 0; n < 8; n++) {
        float wo = Wout[n * 16 + c16];
#pragma unroll
        for (int r = 0; r < 4; r++) part[r] += fmaxf(acc[n][r], 0.f) * wo;
    }
#pragma unroll
    for (int m = 1; m < 16; m <<= 1) {
#pragma unroll
        for (int r = 0; r < 4; r++) part[r] += __shfl_xor(part[r], m, 64);
    }
    if (c16 == 0) {
        float bo = bout[0];
#pragma unroll
        for (int r = 0; r < 4; r++) {
            int orow = rbase + quad * 4 + r;
            if (orow < N_NODES) out[orow] = part[r] + bo;
        }
    }
}

// ---------------- launch ----------------

extern "C" void kernel_launch(void* const* d_in, const int* in_sizes, int n_in,
                              void* d_out, int out_size, void* d_ws, size_t ws_size,
                              hipStream_t stream) {
    const float* X    = (const float*)d_in[0];
    const int*   row  = (const int*)d_in[1];
    const int*   col  = (const int*)d_in[2];
    const float* vals = (const float*)d_in[3];
    const float* W_in = (const float*)d_in[4];
    const float* b_in = (const float*)d_in[5];
    const float* W1   = (const float*)d_in[6];
    const float* W2   = (const float*)d_in[7];
    const float* Wout = (const float*)d_in[8];
    const float* bout = (const float*)d_in[9];
    float* out = (float*)d_out;

    char* ws = (char*)d_ws;
    size_t off = 0;
    auto alloc = [&](size_t bytes) -> void* {
        void* p = ws + off;
        off += (bytes + 511) & ~(size_t)511;
        return p;
    };
    unsigned short* Hb  = (unsigned short*)alloc((size_t)N_NODES * 128 * 2);  // H bf16
    unsigned short* AHb = (unsigned short*)alloc((size_t)N_NODES * 128 * 2);  // AH bf16
    float*          A2f = (float*)alloc((size_t)N_NODES * 128 * 4);           // A2H fp32
    int2*  evf     = (int2*)alloc((size_t)N_EDGES * 8);
    short* Wtin    = (short*)alloc(128 * 128 * 2);
    short* Wt1     = (short*)alloc(128 * 128 * 2);
    short* Wt2     = (short*)alloc(128 * 128 * 2);
    int*   deg     = (int*)alloc((size_t)N_NODES * 4);
    int*   row_ptr = (int*)alloc((size_t)(N_NODES + 1) * 4);
    int*   nxt     = (int*)alloc((size_t)N_NODES * 4);
    int*   bsum    = (int*)alloc(512 * 4);

    hipMemsetAsync(deg, 0, (size_t)N_NODES * 4, stream);

    int eblk = (N_EDGES + 255) / 256;
    int nb = (N_NODES + 255) / 256;  // 391
    k_hist<<<eblk, 256, 0, stream>>>(row, deg);
    k_scan1<<<nb, 256, 0, stream>>>(deg, row_ptr, bsum);
    k_scan2<<<1, 512, 0, stream>>>(bsum, nb);
    k_scan3<<<nb, 256, 0, stream>>>(row_ptr, bsum, nxt);
    k_scatter<<<eblk, 256, 0, stream>>>(row, col, vals, nxt, evf);

    k_cvtw<<<64, 256, 0, stream>>>(W_in, Wtin);
    k_cvtw<<<64, 256, 0, stream>>>(W1, Wt1);
    k_cvtw<<<64, 256, 0, stream>>>(W2, Wt2);

    int gblk = (N_NODES + 63) / 64;  // 1563
    k_gemm_in<<<gblk, 256, 0, stream>>>(X, Wtin, b_in, Hb);

    int sblk = (N_NODES + 3) / 4;  // 4 waves/block, 1 row/wave
    k_spmm_t<0><<<sblk, 256, 0, stream>>>(row_ptr, evf, (const unsigned*)Hb,
                                          (unsigned*)AHb, nullptr);
    k_spmm_t<1><<<sblk, 256, 0, stream>>>(row_ptr, evf, (const unsigned*)AHb,
                                          nullptr, (float2*)A2f);

    k_gemm_out<<<gblk, 256, 0, stream>>>(AHb, A2f, Wt1, Wt2, Wout, bout, out);
}

// Round 4
// 402.819 us; speedup vs baseline: 6.2561x; 1.3223x over previous
//
#include <hip/hip_runtime.h>

#define N_NODES 100000
#define N_EDGES 1600000
#define NBUCK 391   // ceil(N_NODES / 256) buckets of 256 rows
#define NCHUNK 256  // blocks in passes A/C
#define CHUNK 6250  // N_EDGES / NCHUNK exactly

typedef float f32x4 __attribute__((ext_vector_type(4)));
typedef short bf16x8 __attribute__((ext_vector_type(8)));

// fp32 -> bf16 round-to-nearest-even, bits in low 16.
__device__ __forceinline__ unsigned f2bf_bits(float f) {
    unsigned u = __float_as_uint(f);
    u += 0x7fffu + ((u >> 16) & 1u);
    return u >> 16;
}
__device__ __forceinline__ float bf_lo(unsigned u) { return __uint_as_float(u << 16); }
__device__ __forceinline__ float bf_hi(unsigned u) { return __uint_as_float(u & 0xffff0000u); }

__device__ __forceinline__ bf16x8 pack_bf8(float4 a, float4 b) {
    bf16x8 r;
    r[0] = (short)f2bf_bits(a.x); r[1] = (short)f2bf_bits(a.y);
    r[2] = (short)f2bf_bits(a.z); r[3] = (short)f2bf_bits(a.w);
    r[4] = (short)f2bf_bits(b.x); r[5] = (short)f2bf_bits(b.y);
    r[6] = (short)f2bf_bits(b.z); r[7] = (short)f2bf_bits(b.w);
    return r;
}

// ============ CSR build: bucket binning, zero contended global atomics ======

// Pass A: per-chunk LDS histogram over buckets -> hmat[blk][b] (plain stores).
__global__ __launch_bounds__(256) void k_binA(const int* __restrict__ row,
                                              int* __restrict__ hmat) {
    __shared__ int h[NBUCK];
    for (int i = threadIdx.x; i < NBUCK; i += 256) h[i] = 0;
    __syncthreads();
    int s = blockIdx.x * CHUNK, e = s + CHUNK;
    for (int i = s + threadIdx.x; i < e; i += 256)
        atomicAdd(&h[row[i] >> 8], 1);
    __syncthreads();
    for (int b = threadIdx.x; b < NBUCK; b += 256)
        hmat[blockIdx.x * NBUCK + b] = h[b];
}

// Per-bucket exclusive scan over blocks: bases[blk][b], totals -> bcnt[b].
__global__ __launch_bounds__(256) void k_colscan(const int* __restrict__ hmat,
                                                 int* __restrict__ bases,
                                                 int* __restrict__ bcnt) {
    __shared__ int s[256];
    int b = blockIdx.x, t = threadIdx.x;
    int v = hmat[t * NBUCK + b];
    s[t] = v;
    __syncthreads();
    for (int off = 1; off < 256; off <<= 1) {
        int x = (t >= off) ? s[t - off] : 0;
        __syncthreads();
        s[t] += x;
        __syncthreads();
    }
    bases[t * NBUCK + b] = s[t] - v;
    if (t == 255) bcnt[b] = s[255];
}

// Exclusive scan of 391 bucket totals -> bstart[0..391].
__global__ void k_scanB(const int* __restrict__ bcnt, int* __restrict__ bstart) {
    __shared__ int s[512];
    int t = threadIdx.x;
    int v = (t < NBUCK) ? bcnt[t] : 0;
    s[t] = v;
    __syncthreads();
    for (int off = 1; off < 512; off <<= 1) {
        int x = (t >= off) ? s[t - off] : 0;
        __syncthreads();
        s[t] += x;
        __syncthreads();
    }
    if (t < NBUCK) bstart[t] = s[t] - v;
    if (t == NBUCK) bstart[NBUCK] = N_EDGES;
}

// Pass C: re-read chunk, LDS-rank within block, write bucket-grouped edges.
// grouped[i] = {col, (row&255)<<15 | q15(val)}. Same-line stores are block-local
// in time -> L2 merges -> low write amplification.
__global__ __launch_bounds__(256) void k_binC(const int* __restrict__ row,
                                              const int* __restrict__ col,
                                              const float* __restrict__ vals,
                                              const int* __restrict__ bstart,
                                              const int* __restrict__ bases,
                                              int2* __restrict__ grouped) {
    __shared__ int cnt[NBUCK];
    for (int i = threadIdx.x; i < NBUCK; i += 256) cnt[i] = 0;
    __syncthreads();
    int s = blockIdx.x * CHUNK, e = s + CHUNK;
    for (int i = s + threadIdx.x; i < e; i += 256) {
        int r = row[i];
        int b = r >> 8;
        int rank = atomicAdd(&cnt[b], 1);
        int pos = bstart[b] + bases[blockIdx.x * NBUCK + b] + rank;
        int q = __float2int_rn(vals[i] * 32768.f);
        if (q > 32767) q = 32767;
        grouped[pos] = make_int2(col[i], ((r & 255) << 15) | q);
    }
}

// Pass D: one block per bucket. LDS row-hist + scan -> row_ptr (no global
// scan), then scatter into final CSR order inside a ~16KB window.
// Final edge = 4B: col<<15 | q15(val).
__global__ __launch_bounds__(256) void k_binD(const int2* __restrict__ grouped,
                                              const int* __restrict__ bstart,
                                              unsigned* __restrict__ evf,
                                              int* __restrict__ row_ptr) {
    __shared__ int h[256], sc[256], cur[256];
    int b = blockIdx.x, t = threadIdx.x;
    h[t] = 0;
    __syncthreads();
    int s0 = bstart[b], e0 = bstart[b + 1];
    for (int i = s0 + t; i < e0; i += 256)
        atomicAdd(&h[(grouped[i].y >> 15) & 255], 1);
    __syncthreads();
    int v = h[t];
    sc[t] = v;
    __syncthreads();
    for (int off = 1; off < 256; off <<= 1) {
        int x = (t >= off) ? sc[t - off] : 0;
        __syncthreads();
        sc[t] += x;
        __syncthreads();
    }
    int excl = sc[t] - v;
    cur[t] = excl;
    int grow = b * 256 + t;
    if (grow <= N_NODES) row_ptr[grow] = s0 + excl;  // last bucket: rows>=N have h=0
    __syncthreads();
    for (int i = s0 + t; i < e0; i += 256) {
        int2 g = grouped[i];
        int rl = (g.y >> 15) & 255;
        int p = atomicAdd(&cur[rl], 1);
        evf[s0 + p] = ((unsigned)g.x << 15) | (unsigned)(g.y & 32767);
    }
}

// ---------------- weight convert+transpose: Wt[n][k] = bf16(W[k][n]) -------
__global__ void k_cvtw3(const float* __restrict__ Wa, const float* __restrict__ Wb,
                        const float* __restrict__ Wc, short* __restrict__ Wta,
                        short* __restrict__ Wtb, short* __restrict__ Wtc) {
    int t = blockIdx.x * 256 + threadIdx.x;
    int which = t >> 14;
    int i = t & 16383;
    int n = i & 127, k = i >> 7;
    const float* W = which == 0 ? Wa : which == 1 ? Wb : Wc;
    short* Wt = which == 0 ? Wta : which == 1 ? Wtb : Wtc;
    Wt[n * 128 + k] = (short)f2bf_bits(W[k * 128 + n]);
}

// ---------------- GEMM1: H(bf16) = relu(X @ W_in + b_in), MFMA -------------
__global__ __launch_bounds__(256) void k_gemm_in(const float* __restrict__ X,
                                                 const short* __restrict__ Wt,
                                                 const float* __restrict__ b,
                                                 unsigned short* __restrict__ H) {
    __shared__ unsigned short st[4][16 * 128];
    int lane = threadIdx.x & 63, wv = threadIdx.x >> 6;
    int quad = lane >> 4, c16 = lane & 15;
    int rbase = blockIdx.x * 64 + wv * 16;
    int arow = rbase + c16;
    bool aok = arow < N_NODES;
    const float4* Xg = (const float4*)X;

    f32x4 acc[8] = {};
#pragma unroll
    for (int kc = 0; kc < 4; kc++) {
        float4 f0 = make_float4(0.f, 0.f, 0.f, 0.f), f1 = f0;
        if (aok) {
            f0 = Xg[(size_t)arow * 32 + kc * 8 + quad * 2];
            f1 = Xg[(size_t)arow * 32 + kc * 8 + quad * 2 + 1];
        }
        bf16x8 af = pack_bf8(f0, f1);
#pragma unroll
        for (int n = 0; n < 8; n++) {
            bf16x8 bf = *(const bf16x8*)&Wt[(n * 16 + c16) * 128 + kc * 32 + quad * 8];
            acc[n] = __builtin_amdgcn_mfma_f32_16x16x32_bf16(af, bf, acc[n], 0, 0, 0);
        }
    }

#pragma unroll
    for (int n = 0; n < 8; n++) {
        float bb = b[n * 16 + c16];
#pragma unroll
        for (int r = 0; r < 4; r++) {
            float v = fmaxf(acc[n][r] + bb, 0.f);
            st[wv][(quad * 4 + r) * 128 + n * 16 + c16] = (unsigned short)f2bf_bits(v);
        }
    }
    __syncthreads();
    int t = threadIdx.x;
    int lrow = t >> 2;
    int orow = blockIdx.x * 64 + lrow;
    if (orow < N_NODES) {
        const int4* src = (const int4*)&st[lrow >> 4][(lrow & 15) * 128 + (t & 3) * 32];
        int4* dst = (int4*)&H[(size_t)orow * 128 + (t & 3) * 32];
        dst[0] = src[0]; dst[1] = src[1]; dst[2] = src[2]; dst[3] = src[3];
    }
}

// ---------------- SpMM: wave per row, bf16 gather, fp32 accumulate ---------
template <int OUTF32>
__global__ __launch_bounds__(256) void k_spmm_t(const int* __restrict__ rp,
                                                const unsigned* __restrict__ evf,
                                                const unsigned* __restrict__ Hin,
                                                unsigned* __restrict__ HoB,
                                                float2* __restrict__ HoF) {
    int wid = (blockIdx.x * blockDim.x + threadIdx.x) >> 6;
    int lane = threadIdx.x & 63;
    if (wid >= N_NODES) return;
    int s = __builtin_amdgcn_readfirstlane(rp[wid]);
    int e = __builtin_amdgcn_readfirstlane(rp[wid + 1]);
    float ax = 0.f, ay = 0.f;
    int j = s;
    for (; j + 1 < e; j += 2) {
        unsigned u0 = evf[j], u1 = evf[j + 1];
        unsigned h0 = Hin[(size_t)(u0 >> 15) * 64 + lane];
        unsigned h1 = Hin[(size_t)(u1 >> 15) * 64 + lane];
        float v0 = (float)(u0 & 32767u) * (1.f / 32768.f);
        float v1 = (float)(u1 & 32767u) * (1.f / 32768.f);
        ax += v0 * bf_lo(h0) + v1 * bf_lo(h1);
        ay += v0 * bf_hi(h0) + v1 * bf_hi(h1);
    }
    if (j < e) {
        unsigned u0 = evf[j];
        unsigned h0 = Hin[(size_t)(u0 >> 15) * 64 + lane];
        float v0 = (float)(u0 & 32767u) * (1.f / 32768.f);
        ax += v0 * bf_lo(h0);
        ay += v0 * bf_hi(h0);
    }
    if (OUTF32) {
        HoF[(size_t)wid * 64 + lane] = make_float2(ax, ay);
    } else {
        HoB[(size_t)wid * 64 + lane] = (f2bf_bits(ay) << 16) | f2bf_bits(ax);
    }
}

// ------- Final: out = relu(AH@W1 + A2H@W2) @ W_out + b_out, MFMA fused -----
__global__ __launch_bounds__(256) void k_gemm_out(const unsigned short* __restrict__ AH,
                                                  const float* __restrict__ A2H,
                                                  const short* __restrict__ Wt1,
                                                  const short* __restrict__ Wt2,
                                                  const float* __restrict__ Wout,
                                                  const float* __restrict__ bout,
                                                  float* __restrict__ out) {
    int lane = threadIdx.x & 63, wv = threadIdx.x >> 6;
    int quad = lane >> 4, c16 = lane & 15;
    int rbase = blockIdx.x * 64 + wv * 16;
    int arow = rbase + c16;
    bool aok = arow < N_NODES;
    const float4* A2g = (const float4*)A2H;

    f32x4 acc[8] = {};
#pragma unroll
    for (int kc = 0; kc < 4; kc++) {
        bf16x8 afA = {};
        float4 f0 = make_float4(0.f, 0.f, 0.f, 0.f), f1 = f0;
        if (aok) {
            afA = *(const bf16x8*)&AH[(size_t)arow * 128 + kc * 32 + quad * 8];
            f0 = A2g[(size_t)arow * 32 + kc * 8 + quad * 2];
            f1 = A2g[(size_t)arow * 32 + kc * 8 + quad * 2 + 1];
        }
        bf16x8 afB = pack_bf8(f0, f1);
#pragma unroll
        for (int n = 0; n < 8; n++) {
            bf16x8 b1 = *(const bf16x8*)&Wt1[(n * 16 + c16) * 128 + kc * 32 + quad * 8];
            bf16x8 b2 = *(const bf16x8*)&Wt2[(n * 16 + c16) * 128 + kc * 32 + quad * 8];
            acc[n] = __builtin_amdgcn_mfma_f32_16x16x32_bf16(afA, b1, acc[n], 0, 0, 0);
            acc[n] = __builtin_amdgcn_mfma_f32_16x16x32_bf16(afB, b2, acc[n], 0, 0, 0);
        }
    }

    float part[4] = {0.f, 0.f, 0.f, 0.f};
#pragma unroll
    for (int n = 0; n < 8; n++) {
        float wo = Wout[n * 16 + c16];
#pragma unroll
        for (int r = 0; r < 4; r++) part[r] += fmaxf(acc[n][r], 0.f) * wo;
    }
#pragma unroll
    for (int m = 1; m < 16; m <<= 1) {
#pragma unroll
        for (int r = 0; r < 4; r++) part[r] += __shfl_xor(part[r], m, 64);
    }
    if (c16 == 0) {
        float bo = bout[0];
#pragma unroll
        for (int r = 0; r < 4; r++) {
            int orow = rbase + quad * 4 + r;
            if (orow < N_NODES) out[orow] = part[r] + bo;
        }
    }
}

// ---------------- launch ----------------

extern "C" void kernel_launch(void* const* d_in, const int* in_sizes, int n_in,
                              void* d_out, int out_size, void* d_ws, size_t ws_size,
                              hipStream_t stream) {
    const float* X    = (const float*)d_in[0];
    const int*   row  = (const int*)d_in[1];
    const int*   col  = (const int*)d_in[2];
    const float* vals = (const float*)d_in[3];
    const float* W_in = (const float*)d_in[4];
    const float* b_in = (const float*)d_in[5];
    const float* W1   = (const float*)d_in[6];
    const float* W2   = (const float*)d_in[7];
    const float* Wout = (const float*)d_in[8];
    const float* bout = (const float*)d_in[9];
    float* out = (float*)d_out;

    char* ws = (char*)d_ws;
    size_t off = 0;
    auto alloc = [&](size_t bytes) -> void* {
        void* p = ws + off;
        off += (bytes + 511) & ~(size_t)511;
        return p;
    };
    unsigned short* Hb  = (unsigned short*)alloc((size_t)N_NODES * 128 * 2);  // H bf16
    unsigned short* AHb = (unsigned short*)alloc((size_t)N_NODES * 128 * 2);  // AH bf16
    float*          A2f = (float*)alloc((size_t)N_NODES * 128 * 4);           // A2H fp32
    unsigned* evf  = (unsigned*)alloc((size_t)N_EDGES * 4);
    short* Wtin    = (short*)alloc(128 * 128 * 2);
    short* Wt1     = (short*)alloc(128 * 128 * 2);
    short* Wt2     = (short*)alloc(128 * 128 * 2);
    int*   hmat    = (int*)alloc((size_t)NCHUNK * NBUCK * 4);
    int*   bases   = (int*)alloc((size_t)NCHUNK * NBUCK * 4);
    int*   bcnt    = (int*)alloc(512 * 4);
    int*   bstart  = (int*)alloc(512 * 4);
    int*   row_ptr = (int*)alloc((size_t)(N_NODES + 256) * 4);
    // grouped (12.8MB) aliases A2f (51.2MB): dead before k_spmm_t<1> writes A2f.
    int2* grouped = (int2*)A2f;

    k_binA<<<NCHUNK, 256, 0, stream>>>(row, hmat);
    k_colscan<<<NBUCK, 256, 0, stream>>>(hmat, bases, bcnt);
    k_scanB<<<1, 512, 0, stream>>>(bcnt, bstart);
    k_binC<<<NCHUNK, 256, 0, stream>>>(row, col, vals, bstart, bases, grouped);
    k_binD<<<NBUCK, 256, 0, stream>>>(grouped, bstart, evf, row_ptr);

    k_cvtw3<<<192, 256, 0, stream>>>(W_in, W1, W2, Wtin, Wt1, Wt2);

    int gblk = (N_NODES + 63) / 64;  // 1563
    k_gemm_in<<<gblk, 256, 0, stream>>>(X, Wtin, b_in, Hb);

    int sblk = (N_NODES + 3) / 4;  // 4 waves/block, 1 row/wave
    k_spmm_t<0><<<sblk, 256, 0, stream>>>(row_ptr, evf, (const unsigned*)Hb,
                                          (unsigned*)AHb, nullptr);
    k_spmm_t<1><<<sblk, 256, 0, stream>>>(row_ptr, evf, (const unsigned*)AHb,
                                          nullptr, (float2*)A2f);

    k_gemm_out<<<gblk, 256, 0, stream>>>(AHb, A2f, Wt1, Wt2, Wout, bout, out);
}

// Round 5
// 391.895 us; speedup vs baseline: 6.4305x; 1.0279x over previous
//
#include <hip/hip_runtime.h>

#define N_NODES 100000
#define N_EDGES 1600000
#define NBUCK 391   // ceil(N_NODES / 256) buckets of 256 rows
#define NCHUNK 256  // blocks in passes A/C
#define CHUNK 6250  // N_EDGES / NCHUNK exactly

typedef float f32x4 __attribute__((ext_vector_type(4)));
typedef short bf16x8 __attribute__((ext_vector_type(8)));

// fp32 -> bf16 round-to-nearest-even, bits in low 16.
__device__ __forceinline__ unsigned f2bf_bits(float f) {
    unsigned u = __float_as_uint(f);
    u += 0x7fffu + ((u >> 16) & 1u);
    return u >> 16;
}
__device__ __forceinline__ float bf_lo(unsigned u) { return __uint_as_float(u << 16); }
__device__ __forceinline__ float bf_hi(unsigned u) { return __uint_as_float(u & 0xffff0000u); }

__device__ __forceinline__ bf16x8 pack_bf8(float4 a, float4 b) {
    bf16x8 r;
    r[0] = (short)f2bf_bits(a.x); r[1] = (short)f2bf_bits(a.y);
    r[2] = (short)f2bf_bits(a.z); r[3] = (short)f2bf_bits(a.w);
    r[4] = (short)f2bf_bits(b.x); r[5] = (short)f2bf_bits(b.y);
    r[6] = (short)f2bf_bits(b.z); r[7] = (short)f2bf_bits(b.w);
    return r;
}

// ============ CSR build: bucket binning, zero contended global atomics ======

__global__ __launch_bounds__(256) void k_binA(const int* __restrict__ row,
                                              int* __restrict__ hmat) {
    __shared__ int h[NBUCK];
    for (int i = threadIdx.x; i < NBUCK; i += 256) h[i] = 0;
    __syncthreads();
    int s = blockIdx.x * CHUNK, e = s + CHUNK;
    for (int i = s + threadIdx.x; i < e; i += 256)
        atomicAdd(&h[row[i] >> 8], 1);
    __syncthreads();
    for (int b = threadIdx.x; b < NBUCK; b += 256)
        hmat[blockIdx.x * NBUCK + b] = h[b];
}

__global__ __launch_bounds__(256) void k_colscan(const int* __restrict__ hmat,
                                                 int* __restrict__ bases,
                                                 int* __restrict__ bcnt) {
    __shared__ int s[256];
    int b = blockIdx.x, t = threadIdx.x;
    int v = hmat[t * NBUCK + b];
    s[t] = v;
    __syncthreads();
    for (int off = 1; off < 256; off <<= 1) {
        int x = (t >= off) ? s[t - off] : 0;
        __syncthreads();
        s[t] += x;
        __syncthreads();
    }
    bases[t * NBUCK + b] = s[t] - v;
    if (t == 255) bcnt[b] = s[255];
}

__global__ void k_scanB(const int* __restrict__ bcnt, int* __restrict__ bstart) {
    __shared__ int s[512];
    int t = threadIdx.x;
    int v = (t < NBUCK) ? bcnt[t] : 0;
    s[t] = v;
    __syncthreads();
    for (int off = 1; off < 512; off <<= 1) {
        int x = (t >= off) ? s[t - off] : 0;
        __syncthreads();
        s[t] += x;
        __syncthreads();
    }
    if (t < NBUCK) bstart[t] = s[t] - v;
    if (t == NBUCK) bstart[NBUCK] = N_EDGES;
}

__global__ __launch_bounds__(256) void k_binC(const int* __restrict__ row,
                                              const int* __restrict__ col,
                                              const float* __restrict__ vals,
                                              const int* __restrict__ bstart,
                                              const int* __restrict__ bases,
                                              int2* __restrict__ grouped) {
    __shared__ int cnt[NBUCK];
    for (int i = threadIdx.x; i < NBUCK; i += 256) cnt[i] = 0;
    __syncthreads();
    int s = blockIdx.x * CHUNK, e = s + CHUNK;
    for (int i = s + threadIdx.x; i < e; i += 256) {
        int r = row[i];
        int b = r >> 8;
        int rank = atomicAdd(&cnt[b], 1);
        int pos = bstart[b] + bases[blockIdx.x * NBUCK + b] + rank;
        int q = __float2int_rn(vals[i] * 32768.f);
        if (q > 32767) q = 32767;
        grouped[pos] = make_int2(col[i], ((r & 255) << 15) | q);
    }
}

__global__ __launch_bounds__(256) void k_binD(const int2* __restrict__ grouped,
                                              const int* __restrict__ bstart,
                                              unsigned* __restrict__ evf,
                                              int* __restrict__ row_ptr) {
    __shared__ int h[256], sc[256], cur[256];
    int b = blockIdx.x, t = threadIdx.x;
    h[t] = 0;
    __syncthreads();
    int s0 = bstart[b], e0 = bstart[b + 1];
    for (int i = s0 + t; i < e0; i += 256)
        atomicAdd(&h[(grouped[i].y >> 15) & 255], 1);
    __syncthreads();
    int v = h[t];
    sc[t] = v;
    __syncthreads();
    for (int off = 1; off < 256; off <<= 1) {
        int x = (t >= off) ? sc[t - off] : 0;
        __syncthreads();
        sc[t] += x;
        __syncthreads();
    }
    int excl = sc[t] - v;
    cur[t] = excl;
    int grow = b * 256 + t;
    if (grow <= N_NODES) row_ptr[grow] = s0 + excl;
    __syncthreads();
    for (int i = s0 + t; i < e0; i += 256) {
        int2 g = grouped[i];
        int rl = (g.y >> 15) & 255;
        int p = atomicAdd(&cur[rl], 1);
        evf[s0 + p] = ((unsigned)g.x << 15) | (unsigned)(g.y & 32767);
    }
}

// ---------------- weight convert+transpose: Wt[n][k] = bf16(W[k][n]) -------
__global__ void k_cvtw3(const float* __restrict__ Wa, const float* __restrict__ Wb,
                        const float* __restrict__ Wc, short* __restrict__ Wta,
                        short* __restrict__ Wtb, short* __restrict__ Wtc) {
    int t = blockIdx.x * 256 + threadIdx.x;
    int which = t >> 14;
    int i = t & 16383;
    int n = i & 127, k = i >> 7;
    const float* W = which == 0 ? Wa : which == 1 ? Wb : Wc;
    short* Wt = which == 0 ? Wta : which == 1 ? Wtb : Wtc;
    Wt[n * 128 + k] = (short)f2bf_bits(W[k * 128 + n]);
}

// ---------------- GEMM1: H(bf16) = relu(X @ W_in + b_in), MFMA -------------
__global__ __launch_bounds__(256) void k_gemm_in(const float* __restrict__ X,
                                                 const short* __restrict__ Wt,
                                                 const float* __restrict__ b,
                                                 unsigned short* __restrict__ H) {
    __shared__ unsigned short st[4][16 * 128];
    int lane = threadIdx.x & 63, wv = threadIdx.x >> 6;
    int quad = lane >> 4, c16 = lane & 15;
    int rbase = blockIdx.x * 64 + wv * 16;
    int arow = rbase + c16;
    bool aok = arow < N_NODES;
    const float4* Xg = (const float4*)X;

    f32x4 acc[8] = {};
#pragma unroll
    for (int kc = 0; kc < 4; kc++) {
        float4 f0 = make_float4(0.f, 0.f, 0.f, 0.f), f1 = f0;
        if (aok) {
            f0 = Xg[(size_t)arow * 32 + kc * 8 + quad * 2];
            f1 = Xg[(size_t)arow * 32 + kc * 8 + quad * 2 + 1];
        }
        bf16x8 af = pack_bf8(f0, f1);
#pragma unroll
        for (int n = 0; n < 8; n++) {
            bf16x8 bf = *(const bf16x8*)&Wt[(n * 16 + c16) * 128 + kc * 32 + quad * 8];
            acc[n] = __builtin_amdgcn_mfma_f32_16x16x32_bf16(af, bf, acc[n], 0, 0, 0);
        }
    }

#pragma unroll
    for (int n = 0; n < 8; n++) {
        float bb = b[n * 16 + c16];
#pragma unroll
        for (int r = 0; r < 4; r++) {
            float v = fmaxf(acc[n][r] + bb, 0.f);
            st[wv][(quad * 4 + r) * 128 + n * 16 + c16] = (unsigned short)f2bf_bits(v);
        }
    }
    __syncthreads();
    int t = threadIdx.x;
    int lrow = t >> 2;
    int orow = blockIdx.x * 64 + lrow;
    if (orow < N_NODES) {
        const int4* src = (const int4*)&st[lrow >> 4][(lrow & 15) * 128 + (t & 3) * 32];
        int4* dst = (int4*)&H[(size_t)orow * 128 + (t & 3) * 32];
        dst[0] = src[0]; dst[1] = src[1]; dst[2] = src[2]; dst[3] = src[3];
    }
}

// ------- SpMM: wave per row, HALF-WAVE per edge (2 edges/gather instr) ------
// Lanes 0-31 take edge j, lanes 32-63 edge j+1; each lane loads uint2 (4 bf16
// cols). Cross-half shfl_xor fold at the end. fp32 accumulate, bf16 out.
__global__ __launch_bounds__(256) void k_spmm(const int* __restrict__ rp,
                                              const unsigned* __restrict__ evf,
                                              const unsigned* __restrict__ Hin,
                                              unsigned* __restrict__ Ho) {
    int wid = (blockIdx.x * blockDim.x + threadIdx.x) >> 6;
    int lane = threadIdx.x & 63;
    if (wid >= N_NODES) return;
    int half = lane >> 5, l32 = lane & 31;
    int s = __builtin_amdgcn_readfirstlane(rp[wid]);
    int e = __builtin_amdgcn_readfirstlane(rp[wid + 1]);
    float a0 = 0.f, a1 = 0.f, a2 = 0.f, a3 = 0.f;
    int j = s;
    // main: 4 edges/iter -> 2 independent 2-edge gathers in flight
    for (; j + 4 <= e; j += 4) {
        unsigned ua = evf[j + half];
        unsigned ub = evf[j + 2 + half];
        uint2 ha = *(const uint2*)&Hin[(size_t)(ua >> 15) * 64 + l32 * 2];
        uint2 hb = *(const uint2*)&Hin[(size_t)(ub >> 15) * 64 + l32 * 2];
        float va = (float)(ua & 32767u);
        float vb = (float)(ub & 32767u);
        a0 += va * bf_lo(ha.x) + vb * bf_lo(hb.x);
        a1 += va * bf_hi(ha.x) + vb * bf_hi(hb.x);
        a2 += va * bf_lo(ha.y) + vb * bf_lo(hb.y);
        a3 += va * bf_hi(ha.y) + vb * bf_hi(hb.y);
    }
    if (j + 2 <= e) {
        unsigned ua = evf[j + half];
        uint2 ha = *(const uint2*)&Hin[(size_t)(ua >> 15) * 64 + l32 * 2];
        float va = (float)(ua & 32767u);
        a0 += va * bf_lo(ha.x);
        a1 += va * bf_hi(ha.x);
        a2 += va * bf_lo(ha.y);
        a3 += va * bf_hi(ha.y);
        j += 2;
    }
    if (j < e && half == 0) {
        unsigned ua = evf[j];
        uint2 ha = *(const uint2*)&Hin[(size_t)(ua >> 15) * 64 + l32 * 2];
        float va = (float)(ua & 32767u);
        a0 += va * bf_lo(ha.x);
        a1 += va * bf_hi(ha.x);
        a2 += va * bf_lo(ha.y);
        a3 += va * bf_hi(ha.y);
    }
    a0 += __shfl_xor(a0, 32, 64);
    a1 += __shfl_xor(a1, 32, 64);
    a2 += __shfl_xor(a2, 32, 64);
    a3 += __shfl_xor(a3, 32, 64);
    if (half == 0) {
        const float sc = 1.f / 32768.f;
        unsigned p0 = (f2bf_bits(a1 * sc) << 16) | f2bf_bits(a0 * sc);
        unsigned p1 = (f2bf_bits(a3 * sc) << 16) | f2bf_bits(a2 * sc);
        *(uint2*)&Ho[(size_t)wid * 64 + l32 * 2] = make_uint2(p0, p1);
    }
}

// ------- Final: out = relu(AH@W1 + A2H@W2) @ W_out + b_out, MFMA fused -----
__global__ __launch_bounds__(256) void k_gemm_out(const unsigned short* __restrict__ AH,
                                                  const unsigned short* __restrict__ A2H,
                                                  const short* __restrict__ Wt1,
                                                  const short* __restrict__ Wt2,
                                                  const float* __restrict__ Wout,
                                                  const float* __restrict__ bout,
                                                  float* __restrict__ out) {
    int lane = threadIdx.x & 63, wv = threadIdx.x >> 6;
    int quad = lane >> 4, c16 = lane & 15;
    int rbase = blockIdx.x * 64 + wv * 16;
    int arow = rbase + c16;
    bool aok = arow < N_NODES;

    f32x4 acc[8] = {};
#pragma unroll
    for (int kc = 0; kc < 4; kc++) {
        bf16x8 afA = {}, afB = {};
        if (aok) {
            afA = *(const bf16x8*)&AH[(size_t)arow * 128 + kc * 32 + quad * 8];
            afB = *(const bf16x8*)&A2H[(size_t)arow * 128 + kc * 32 + quad * 8];
        }
#pragma unroll
        for (int n = 0; n < 8; n++) {
            bf16x8 b1 = *(const bf16x8*)&Wt1[(n * 16 + c16) * 128 + kc * 32 + quad * 8];
            bf16x8 b2 = *(const bf16x8*)&Wt2[(n * 16 + c16) * 128 + kc * 32 + quad * 8];
            acc[n] = __builtin_amdgcn_mfma_f32_16x16x32_bf16(afA, b1, acc[n], 0, 0, 0);
            acc[n] = __builtin_amdgcn_mfma_f32_16x16x32_bf16(afB, b2, acc[n], 0, 0, 0);
        }
    }

    float part[4] = {0.f, 0.f, 0.f, 0.f};
#pragma unroll
    for (int n = 0; n < 8; n++) {
        float wo = Wout[n * 16 + c16];
#pragma unroll
        for (int r = 0; r < 4; r++) part[r] += fmaxf(acc[n][r], 0.f) * wo;
    }
#pragma unroll
    for (int m = 1; m < 16; m <<= 1) {
#pragma unroll
        for (int r = 0; r < 4; r++) part[r] += __shfl_xor(part[r], m, 64);
    }
    if (c16 == 0) {
        float bo = bout[0];
#pragma unroll
        for (int r = 0; r < 4; r++) {
            int orow = rbase + quad * 4 + r;
            if (orow < N_NODES) out[orow] = part[r] + bo;
        }
    }
}

// ---------------- launch ----------------

extern "C" void kernel_launch(void* const* d_in, const int* in_sizes, int n_in,
                              void* d_out, int out_size, void* d_ws, size_t ws_size,
                              hipStream_t stream) {
    const float* X    = (const float*)d_in[0];
    const int*   row  = (const int*)d_in[1];
    const int*   col  = (const int*)d_in[2];
    const float* vals = (const float*)d_in[3];
    const float* W_in = (const float*)d_in[4];
    const float* b_in = (const float*)d_in[5];
    const float* W1   = (const float*)d_in[6];
    const float* W2   = (const float*)d_in[7];
    const float* Wout = (const float*)d_in[8];
    const float* bout = (const float*)d_in[9];
    float* out = (float*)d_out;

    char* ws = (char*)d_ws;
    size_t off = 0;
    auto alloc = [&](size_t bytes) -> void* {
        void* p = ws + off;
        off += (bytes + 511) & ~(size_t)511;
        return p;
    };
    unsigned short* Hb  = (unsigned short*)alloc((size_t)N_NODES * 128 * 2);  // H bf16
    unsigned short* AHb = (unsigned short*)alloc((size_t)N_NODES * 128 * 2);  // AH bf16
    unsigned short* A2b = (unsigned short*)alloc((size_t)N_NODES * 128 * 2);  // A2H bf16
    unsigned* evf  = (unsigned*)alloc((size_t)N_EDGES * 4);
    int2* grouped  = (int2*)alloc((size_t)N_EDGES * 8);
    short* Wtin    = (short*)alloc(128 * 128 * 2);
    short* Wt1     = (short*)alloc(128 * 128 * 2);
    short* Wt2     = (short*)alloc(128 * 128 * 2);
    int*   hmat    = (int*)alloc((size_t)NCHUNK * NBUCK * 4);
    int*   bases   = (int*)alloc((size_t)NCHUNK * NBUCK * 4);
    int*   bcnt    = (int*)alloc(512 * 4);
    int*   bstart  = (int*)alloc(512 * 4);
    int*   row_ptr = (int*)alloc((size_t)(N_NODES + 256) * 4);

    k_binA<<<NCHUNK, 256, 0, stream>>>(row, hmat);
    k_colscan<<<NBUCK, 256, 0, stream>>>(hmat, bases, bcnt);
    k_scanB<<<1, 512, 0, stream>>>(bcnt, bstart);
    k_binC<<<NCHUNK, 256, 0, stream>>>(row, col, vals, bstart, bases, grouped);
    k_binD<<<NBUCK, 256, 0, stream>>>(grouped, bstart, evf, row_ptr);

    k_cvtw3<<<192, 256, 0, stream>>>(W_in, W1, W2, Wtin, Wt1, Wt2);

    int gblk = (N_NODES + 63) / 64;  // 1563
    k_gemm_in<<<gblk, 256, 0, stream>>>(X, Wtin, b_in, Hb);

    int sblk = (N_NODES + 3) / 4;  // 4 waves/block, 1 row/wave
    k_spmm<<<sblk, 256, 0, stream>>>(row_ptr, evf, (const unsigned*)Hb, (unsigned*)AHb);
    k_spmm<<<sblk, 256, 0, stream>>>(row_ptr, evf, (const unsigned*)AHb, (unsigned*)A2b);

    k_gemm_out<<<gblk, 256, 0, stream>>>(AHb, A2b, Wt1, Wt2, Wout, bout, out);
}

// Round 6
// 377.285 us; speedup vs baseline: 6.6795x; 1.0387x over previous
//
#include <hip/hip_runtime.h>

#define N_NODES 100000
#define N_EDGES 1600000
#define NBUCK 391   // ceil(N_NODES / 256) buckets of 256 rows
#define NCHUNK 256  // blocks in passes A/C
#define CHUNK 6250  // N_EDGES / NCHUNK exactly

typedef float f32x4 __attribute__((ext_vector_type(4)));
typedef short bf16x8 __attribute__((ext_vector_type(8)));

// fp32 -> bf16 round-to-nearest-even, bits in low 16.
__device__ __forceinline__ unsigned f2bf_bits(float f) {
    unsigned u = __float_as_uint(f);
    u += 0x7fffu + ((u >> 16) & 1u);
    return u >> 16;
}
__device__ __forceinline__ float bf_lo(unsigned u) { return __uint_as_float(u << 16); }
__device__ __forceinline__ float bf_hi(unsigned u) { return __uint_as_float(u & 0xffff0000u); }

__device__ __forceinline__ bf16x8 pack_bf8(float4 a, float4 b) {
    bf16x8 r;
    r[0] = (short)f2bf_bits(a.x); r[1] = (short)f2bf_bits(a.y);
    r[2] = (short)f2bf_bits(a.z); r[3] = (short)f2bf_bits(a.w);
    r[4] = (short)f2bf_bits(b.x); r[5] = (short)f2bf_bits(b.y);
    r[6] = (short)f2bf_bits(b.z); r[7] = (short)f2bf_bits(b.w);
    return r;
}

// ============ CSR build: bucket binning, zero contended global atomics ======

__global__ __launch_bounds__(256) void k_binA(const int* __restrict__ row,
                                              int* __restrict__ hmat) {
    __shared__ int h[NBUCK];
    for (int i = threadIdx.x; i < NBUCK; i += 256) h[i] = 0;
    __syncthreads();
    int s = blockIdx.x * CHUNK, e = s + CHUNK;
    for (int i = s + threadIdx.x; i < e; i += 256)
        atomicAdd(&h[row[i] >> 8], 1);
    __syncthreads();
    for (int b = threadIdx.x; b < NBUCK; b += 256)
        hmat[blockIdx.x * NBUCK + b] = h[b];
}

__global__ __launch_bounds__(256) void k_colscan(const int* __restrict__ hmat,
                                                 int* __restrict__ bases,
                                                 int* __restrict__ bcnt) {
    __shared__ int s[256];
    int b = blockIdx.x, t = threadIdx.x;
    int v = hmat[t * NBUCK + b];
    s[t] = v;
    __syncthreads();
    for (int off = 1; off < 256; off <<= 1) {
        int x = (t >= off) ? s[t - off] : 0;
        __syncthreads();
        s[t] += x;
        __syncthreads();
    }
    bases[t * NBUCK + b] = s[t] - v;
    if (t == 255) bcnt[b] = s[255];
}

__global__ void k_scanB(const int* __restrict__ bcnt, int* __restrict__ bstart) {
    __shared__ int s[512];
    int t = threadIdx.x;
    int v = (t < NBUCK) ? bcnt[t] : 0;
    s[t] = v;
    __syncthreads();
    for (int off = 1; off < 512; off <<= 1) {
        int x = (t >= off) ? s[t - off] : 0;
        __syncthreads();
        s[t] += x;
        __syncthreads();
    }
    if (t < NBUCK) bstart[t] = s[t] - v;
    if (t == NBUCK) bstart[NBUCK] = N_EDGES;
}

__global__ __launch_bounds__(256) void k_binC(const int* __restrict__ row,
                                              const int* __restrict__ col,
                                              const float* __restrict__ vals,
                                              const int* __restrict__ bstart,
                                              const int* __restrict__ bases,
                                              int2* __restrict__ grouped) {
    __shared__ int cnt[NBUCK];
    for (int i = threadIdx.x; i < NBUCK; i += 256) cnt[i] = 0;
    __syncthreads();
    int s = blockIdx.x * CHUNK, e = s + CHUNK;
    for (int i = s + threadIdx.x; i < e; i += 256) {
        int r = row[i];
        int b = r >> 8;
        int rank = atomicAdd(&cnt[b], 1);
        int pos = bstart[b] + bases[blockIdx.x * NBUCK + b] + rank;
        int q = __float2int_rn(vals[i] * 32768.f);
        if (q > 32767) q = 32767;
        grouped[pos] = make_int2(col[i], ((r & 255) << 15) | q);
    }
}

__global__ __launch_bounds__(256) void k_binD(const int2* __restrict__ grouped,
                                              const int* __restrict__ bstart,
                                              unsigned* __restrict__ evf,
                                              int* __restrict__ row_ptr) {
    __shared__ int h[256], sc[256], cur[256];
    int b = blockIdx.x, t = threadIdx.x;
    h[t] = 0;
    __syncthreads();
    int s0 = bstart[b], e0 = bstart[b + 1];
    for (int i = s0 + t; i < e0; i += 256)
        atomicAdd(&h[(grouped[i].y >> 15) & 255], 1);
    __syncthreads();
    int v = h[t];
    sc[t] = v;
    __syncthreads();
    for (int off = 1; off < 256; off <<= 1) {
        int x = (t >= off) ? sc[t - off] : 0;
        __syncthreads();
        sc[t] += x;
        __syncthreads();
    }
    int excl = sc[t] - v;
    cur[t] = excl;
    int grow = b * 256 + t;
    if (grow <= N_NODES) row_ptr[grow] = s0 + excl;
    __syncthreads();
    for (int i = s0 + t; i < e0; i += 256) {
        int2 g = grouped[i];
        int rl = (g.y >> 15) & 255;
        int p = atomicAdd(&cur[rl], 1);
        evf[s0 + p] = ((unsigned)g.x << 15) | (unsigned)(g.y & 32767);
    }
}

// ---------------- weight convert+transpose: Wt[n][k] = bf16(W[k][n]) -------
__global__ void k_cvtw3(const float* __restrict__ Wa, const float* __restrict__ Wb,
                        const float* __restrict__ Wc, short* __restrict__ Wta,
                        short* __restrict__ Wtb, short* __restrict__ Wtc) {
    int t = blockIdx.x * 256 + threadIdx.x;
    int which = t >> 14;
    int i = t & 16383;
    int n = i & 127, k = i >> 7;
    const float* W = which == 0 ? Wa : which == 1 ? Wb : Wc;
    short* Wt = which == 0 ? Wta : which == 1 ? Wtb : Wtc;
    Wt[n * 128 + k] = (short)f2bf_bits(W[k * 128 + n]);
}

// ---------------- GEMM1: H(bf16) = relu(X @ W_in + b_in), MFMA -------------
__global__ __launch_bounds__(256) void k_gemm_in(const float* __restrict__ X,
                                                 const short* __restrict__ Wt,
                                                 const float* __restrict__ b,
                                                 unsigned short* __restrict__ H) {
    __shared__ unsigned short st[4][16 * 128];
    int lane = threadIdx.x & 63, wv = threadIdx.x >> 6;
    int quad = lane >> 4, c16 = lane & 15;
    int rbase = blockIdx.x * 64 + wv * 16;
    int arow = rbase + c16;
    bool aok = arow < N_NODES;
    const float4* Xg = (const float4*)X;

    f32x4 acc[8] = {};
#pragma unroll
    for (int kc = 0; kc < 4; kc++) {
        float4 f0 = make_float4(0.f, 0.f, 0.f, 0.f), f1 = f0;
        if (aok) {
            f0 = Xg[(size_t)arow * 32 + kc * 8 + quad * 2];
            f1 = Xg[(size_t)arow * 32 + kc * 8 + quad * 2 + 1];
        }
        bf16x8 af = pack_bf8(f0, f1);
#pragma unroll
        for (int n = 0; n < 8; n++) {
            bf16x8 bf = *(const bf16x8*)&Wt[(n * 16 + c16) * 128 + kc * 32 + quad * 8];
            acc[n] = __builtin_amdgcn_mfma_f32_16x16x32_bf16(af, bf, acc[n], 0, 0, 0);
        }
    }

#pragma unroll
    for (int n = 0; n < 8; n++) {
        float bb = b[n * 16 + c16];
#pragma unroll
        for (int r = 0; r < 4; r++) {
            float v = fmaxf(acc[n][r] + bb, 0.f);
            st[wv][(quad * 4 + r) * 128 + n * 16 + c16] = (unsigned short)f2bf_bits(v);
        }
    }
    __syncthreads();
    int t = threadIdx.x;
    int lrow = t >> 2;
    int orow = blockIdx.x * 64 + lrow;
    if (orow < N_NODES) {
        const int4* src = (const int4*)&st[lrow >> 4][(lrow & 15) * 128 + (t & 3) * 32];
        int4* dst = (int4*)&H[(size_t)orow * 128 + (t & 3) * 32];
        dst[0] = src[0]; dst[1] = src[1]; dst[2] = src[2]; dst[3] = src[3];
    }
}

// ------- SpMM: wave per row, QUARTER-WAVE per edge (4 edges/gather instr) ---
// 16 lanes per edge, each lane uint4 = 8 bf16 cols -> one dwordx4 gather
// covers 4 edges (64 lanes x 16B = 1KB). Unroll 2 -> 8 edges, 2KB in flight
// per wave. Fold across quarters (shfl_xor 16,32); quarter 0 stores uint4.
__global__ __launch_bounds__(256) void k_spmm(const int* __restrict__ rp,
                                              const unsigned* __restrict__ evf,
                                              const unsigned* __restrict__ Hin,
                                              unsigned* __restrict__ Ho) {
    int wid = (blockIdx.x * blockDim.x + threadIdx.x) >> 6;
    int lane = threadIdx.x & 63;
    if (wid >= N_NODES) return;
    int q = lane >> 4, l16 = lane & 15;
    int s = __builtin_amdgcn_readfirstlane(rp[wid]);
    int e = __builtin_amdgcn_readfirstlane(rp[wid + 1]);
    float a0 = 0.f, a1 = 0.f, a2 = 0.f, a3 = 0.f;
    float a4 = 0.f, a5 = 0.f, a6 = 0.f, a7 = 0.f;
    int j = s;
    for (; j + 8 <= e; j += 8) {
        unsigned ua = evf[j + q];
        unsigned ub = evf[j + 4 + q];
        const uint4 ha = *(const uint4*)&Hin[(size_t)(ua >> 15) * 64 + l16 * 4];
        const uint4 hb = *(const uint4*)&Hin[(size_t)(ub >> 15) * 64 + l16 * 4];
        float va = (float)(ua & 32767u);
        float vb = (float)(ub & 32767u);
        a0 += va * bf_lo(ha.x) + vb * bf_lo(hb.x);
        a1 += va * bf_hi(ha.x) + vb * bf_hi(hb.x);
        a2 += va * bf_lo(ha.y) + vb * bf_lo(hb.y);
        a3 += va * bf_hi(ha.y) + vb * bf_hi(hb.y);
        a4 += va * bf_lo(ha.z) + vb * bf_lo(hb.z);
        a5 += va * bf_hi(ha.z) + vb * bf_hi(hb.z);
        a6 += va * bf_lo(ha.w) + vb * bf_lo(hb.w);
        a7 += va * bf_hi(ha.w) + vb * bf_hi(hb.w);
    }
    for (; j < e; j += 4) {  // tail: up to 7 edges, masked
        int idx = j + q;
        unsigned ua = evf[idx < e ? idx : e - 1];
        const uint4 ha = *(const uint4*)&Hin[(size_t)(ua >> 15) * 64 + l16 * 4];
        float va = (idx < e) ? (float)(ua & 32767u) : 0.f;
        a0 += va * bf_lo(ha.x);
        a1 += va * bf_hi(ha.x);
        a2 += va * bf_lo(ha.y);
        a3 += va * bf_hi(ha.y);
        a4 += va * bf_lo(ha.z);
        a5 += va * bf_hi(ha.z);
        a6 += va * bf_lo(ha.w);
        a7 += va * bf_hi(ha.w);
    }
    a0 += __shfl_xor(a0, 16, 64); a0 += __shfl_xor(a0, 32, 64);
    a1 += __shfl_xor(a1, 16, 64); a1 += __shfl_xor(a1, 32, 64);
    a2 += __shfl_xor(a2, 16, 64); a2 += __shfl_xor(a2, 32, 64);
    a3 += __shfl_xor(a3, 16, 64); a3 += __shfl_xor(a3, 32, 64);
    a4 += __shfl_xor(a4, 16, 64); a4 += __shfl_xor(a4, 32, 64);
    a5 += __shfl_xor(a5, 16, 64); a5 += __shfl_xor(a5, 32, 64);
    a6 += __shfl_xor(a6, 16, 64); a6 += __shfl_xor(a6, 32, 64);
    a7 += __shfl_xor(a7, 16, 64); a7 += __shfl_xor(a7, 32, 64);
    if (q == 0) {
        const float sc = 1.f / 32768.f;
        uint4 p;
        p.x = (f2bf_bits(a1 * sc) << 16) | f2bf_bits(a0 * sc);
        p.y = (f2bf_bits(a3 * sc) << 16) | f2bf_bits(a2 * sc);
        p.z = (f2bf_bits(a5 * sc) << 16) | f2bf_bits(a4 * sc);
        p.w = (f2bf_bits(a7 * sc) << 16) | f2bf_bits(a6 * sc);
        *(uint4*)&Ho[(size_t)wid * 64 + l16 * 4] = p;
    }
}

// ------- Final: out = relu(AH@W1 + A2H@W2) @ W_out + b_out, MFMA fused -----
__global__ __launch_bounds__(256) void k_gemm_out(const unsigned short* __restrict__ AH,
                                                  const unsigned short* __restrict__ A2H,
                                                  const short* __restrict__ Wt1,
                                                  const short* __restrict__ Wt2,
                                                  const float* __restrict__ Wout,
                                                  const float* __restrict__ bout,
                                                  float* __restrict__ out) {
    int lane = threadIdx.x & 63, wv = threadIdx.x >> 6;
    int quad = lane >> 4, c16 = lane & 15;
    int rbase = blockIdx.x * 64 + wv * 16;
    int arow = rbase + c16;
    bool aok = arow < N_NODES;

    f32x4 acc[8] = {};
#pragma unroll
    for (int kc = 0; kc < 4; kc++) {
        bf16x8 afA = {}, afB = {};
        if (aok) {
            afA = *(const bf16x8*)&AH[(size_t)arow * 128 + kc * 32 + quad * 8];
            afB = *(const bf16x8*)&A2H[(size_t)arow * 128 + kc * 32 + quad * 8];
        }
#pragma unroll
        for (int n = 0; n < 8; n++) {
            bf16x8 b1 = *(const bf16x8*)&Wt1[(n * 16 + c16) * 128 + kc * 32 + quad * 8];
            bf16x8 b2 = *(const bf16x8*)&Wt2[(n * 16 + c16) * 128 + kc * 32 + quad * 8];
            acc[n] = __builtin_amdgcn_mfma_f32_16x16x32_bf16(afA, b1, acc[n], 0, 0, 0);
            acc[n] = __builtin_amdgcn_mfma_f32_16x16x32_bf16(afB, b2, acc[n], 0, 0, 0);
        }
    }

    float part[4] = {0.f, 0.f, 0.f, 0.f};
#pragma unroll
    for (int n = 0; n < 8; n++) {
        float wo = Wout[n * 16 + c16];
#pragma unroll
        for (int r = 0; r < 4; r++) part[r] += fmaxf(acc[n][r], 0.f) * wo;
    }
#pragma unroll
    for (int m = 1; m < 16; m <<= 1) {
#pragma unroll
        for (int r = 0; r < 4; r++) part[r] += __shfl_xor(part[r], m, 64);
    }
    if (c16 == 0) {
        float bo = bout[0];
#pragma unroll
        for (int r = 0; r < 4; r++) {
            int orow = rbase + quad * 4 + r;
            if (orow < N_NODES) out[orow] = part[r] + bo;
        }
    }
}

// ---------------- launch ----------------

extern "C" void kernel_launch(void* const* d_in, const int* in_sizes, int n_in,
                              void* d_out, int out_size, void* d_ws, size_t ws_size,
                              hipStream_t stream) {
    const float* X    = (const float*)d_in[0];
    const int*   row  = (const int*)d_in[1];
    const int*   col  = (const int*)d_in[2];
    const float* vals = (const float*)d_in[3];
    const float* W_in = (const float*)d_in[4];
    const float* b_in = (const float*)d_in[5];
    const float* W1   = (const float*)d_in[6];
    const float* W2   = (const float*)d_in[7];
    const float* Wout = (const float*)d_in[8];
    const float* bout = (const float*)d_in[9];
    float* out = (float*)d_out;

    char* ws = (char*)d_ws;
    size_t off = 0;
    auto alloc = [&](size_t bytes) -> void* {
        void* p = ws + off;
        off += (bytes + 511) & ~(size_t)511;
        return p;
    };
    unsigned short* Hb  = (unsigned short*)alloc((size_t)N_NODES * 128 * 2);  // H bf16
    unsigned short* AHb = (unsigned short*)alloc((size_t)N_NODES * 128 * 2);  // AH bf16
    unsigned short* A2b = (unsigned short*)alloc((size_t)N_NODES * 128 * 2);  // A2H bf16
    unsigned* evf  = (unsigned*)alloc((size_t)N_EDGES * 4);
    int2* grouped  = (int2*)alloc((size_t)N_EDGES * 8);
    short* Wtin    = (short*)alloc(128 * 128 * 2);
    short* Wt1     = (short*)alloc(128 * 128 * 2);
    short* Wt2     = (short*)alloc(128 * 128 * 2);
    int*   hmat    = (int*)alloc((size_t)NCHUNK * NBUCK * 4);
    int*   bases   = (int*)alloc((size_t)NCHUNK * NBUCK * 4);
    int*   bcnt    = (int*)alloc(512 * 4);
    int*   bstart  = (int*)alloc(512 * 4);
    int*   row_ptr = (int*)alloc((size_t)(N_NODES + 256) * 4);

    k_binA<<<NCHUNK, 256, 0, stream>>>(row, hmat);
    k_colscan<<<NBUCK, 256, 0, stream>>>(hmat, bases, bcnt);
    k_scanB<<<1, 512, 0, stream>>>(bcnt, bstart);
    k_binC<<<NCHUNK, 256, 0, stream>>>(row, col, vals, bstart, bases, grouped);
    k_binD<<<NBUCK, 256, 0, stream>>>(grouped, bstart, evf, row_ptr);

    k_cvtw3<<<192, 256, 0, stream>>>(W_in, W1, W2, Wtin, Wt1, Wt2);

    int gblk = (N_NODES + 63) / 64;  // 1563
    k_gemm_in<<<gblk, 256, 0, stream>>>(X, Wtin, b_in, Hb);

    int sblk = (N_NODES + 3) / 4;  // 4 waves/block, 1 row/wave
    k_spmm<<<sblk, 256, 0, stream>>>(row_ptr, evf, (const unsigned*)Hb, (unsigned*)AHb);
    k_spmm<<<sblk, 256, 0, stream>>>(row_ptr, evf, (const unsigned*)AHb, (unsigned*)A2b);

    k_gemm_out<<<gblk, 256, 0, stream>>>(AHb, A2b, Wt1, Wt2, Wout, bout, out);
}

// Round 7
// 314.829 us; speedup vs baseline: 8.0045x; 1.1984x over previous
//
#include <hip/hip_runtime.h>

#define N_NODES 100000
#define N_EDGES 1600000
#define NBUCK 391   // ceil(N_NODES / 256) buckets of 256 rows
#define NCHUNK 256  // blocks in passes A/C
#define CHUNK 6250  // N_EDGES / NCHUNK exactly
#define LROW 136    // LDS row stride in shorts (272B): optimal bank pattern

typedef float f32x4 __attribute__((ext_vector_type(4)));
typedef short bf16x8 __attribute__((ext_vector_type(8)));

// fp32 -> bf16 round-to-nearest-even, bits in low 16.
__device__ __forceinline__ unsigned f2bf_bits(float f) {
    unsigned u = __float_as_uint(f);
    u += 0x7fffu + ((u >> 16) & 1u);
    return u >> 16;
}
__device__ __forceinline__ float bf_lo(unsigned u) { return __uint_as_float(u << 16); }
__device__ __forceinline__ float bf_hi(unsigned u) { return __uint_as_float(u & 0xffff0000u); }

__device__ __forceinline__ bf16x8 pack_bf8(float4 a, float4 b) {
    bf16x8 r;
    r[0] = (short)f2bf_bits(a.x); r[1] = (short)f2bf_bits(a.y);
    r[2] = (short)f2bf_bits(a.z); r[3] = (short)f2bf_bits(a.w);
    r[4] = (short)f2bf_bits(b.x); r[5] = (short)f2bf_bits(b.y);
    r[6] = (short)f2bf_bits(b.z); r[7] = (short)f2bf_bits(b.w);
    return r;
}

// ============ CSR build: bucket binning, zero contended global atomics ======

__global__ __launch_bounds__(256) void k_binA(const int* __restrict__ row,
                                              int* __restrict__ hmat) {
    __shared__ int h[NBUCK];
    for (int i = threadIdx.x; i < NBUCK; i += 256) h[i] = 0;
    __syncthreads();
    int s = blockIdx.x * CHUNK, e = s + CHUNK;
    for (int i = s + threadIdx.x; i < e; i += 256)
        atomicAdd(&h[row[i] >> 8], 1);
    __syncthreads();
    for (int b = threadIdx.x; b < NBUCK; b += 256)
        hmat[blockIdx.x * NBUCK + b] = h[b];
}

__global__ __launch_bounds__(256) void k_colscan(const int* __restrict__ hmat,
                                                 int* __restrict__ bases,
                                                 int* __restrict__ bcnt) {
    __shared__ int s[256];
    int b = blockIdx.x, t = threadIdx.x;
    int v = hmat[t * NBUCK + b];
    s[t] = v;
    __syncthreads();
    for (int off = 1; off < 256; off <<= 1) {
        int x = (t >= off) ? s[t - off] : 0;
        __syncthreads();
        s[t] += x;
        __syncthreads();
    }
    bases[t * NBUCK + b] = s[t] - v;
    if (t == 255) bcnt[b] = s[255];
}

__global__ void k_scanB(const int* __restrict__ bcnt, int* __restrict__ bstart) {
    __shared__ int s[512];
    int t = threadIdx.x;
    int v = (t < NBUCK) ? bcnt[t] : 0;
    s[t] = v;
    __syncthreads();
    for (int off = 1; off < 512; off <<= 1) {
        int x = (t >= off) ? s[t - off] : 0;
        __syncthreads();
        s[t] += x;
        __syncthreads();
    }
    if (t < NBUCK) bstart[t] = s[t] - v;
    if (t == NBUCK) bstart[NBUCK] = N_EDGES;
}

__global__ __launch_bounds__(256) void k_binC(const int* __restrict__ row,
                                              const int* __restrict__ col,
                                              const float* __restrict__ vals,
                                              const int* __restrict__ bstart,
                                              const int* __restrict__ bases,
                                              int2* __restrict__ grouped) {
    __shared__ int cnt[NBUCK];
    for (int i = threadIdx.x; i < NBUCK; i += 256) cnt[i] = 0;
    __syncthreads();
    int s = blockIdx.x * CHUNK, e = s + CHUNK;
    for (int i = s + threadIdx.x; i < e; i += 256) {
        int r = row[i];
        int b = r >> 8;
        int rank = atomicAdd(&cnt[b], 1);
        int pos = bstart[b] + bases[blockIdx.x * NBUCK + b] + rank;
        int q = __float2int_rn(vals[i] * 32768.f);
        if (q > 32767) q = 32767;
        grouped[pos] = make_int2(col[i], ((r & 255) << 15) | q);
    }
}

__global__ __launch_bounds__(256) void k_binD(const int2* __restrict__ grouped,
                                              const int* __restrict__ bstart,
                                              unsigned* __restrict__ evf,
                                              int* __restrict__ row_ptr) {
    __shared__ int h[256], sc[256], cur[256];
    int b = blockIdx.x, t = threadIdx.x;
    h[t] = 0;
    __syncthreads();
    int s0 = bstart[b], e0 = bstart[b + 1];
    for (int i = s0 + t; i < e0; i += 256)
        atomicAdd(&h[(grouped[i].y >> 15) & 255], 1);
    __syncthreads();
    int v = h[t];
    sc[t] = v;
    __syncthreads();
    for (int off = 1; off < 256; off <<= 1) {
        int x = (t >= off) ? sc[t - off] : 0;
        __syncthreads();
        sc[t] += x;
        __syncthreads();
    }
    int excl = sc[t] - v;
    cur[t] = excl;
    int grow = b * 256 + t;
    if (grow <= N_NODES) row_ptr[grow] = s0 + excl;
    __syncthreads();
    for (int i = s0 + t; i < e0; i += 256) {
        int2 g = grouped[i];
        int rl = (g.y >> 15) & 255;
        int p = atomicAdd(&cur[rl], 1);
        evf[s0 + p] = ((unsigned)g.x << 15) | (unsigned)(g.y & 32767);
    }
}

// ---------------- weight convert+transpose: Wt[n][k] = bf16(W[k][n]) -------
__global__ void k_cvtw3(const float* __restrict__ Wa, const float* __restrict__ Wb,
                        const float* __restrict__ Wc, short* __restrict__ Wta,
                        short* __restrict__ Wtb, short* __restrict__ Wtc) {
    int t = blockIdx.x * 256 + threadIdx.x;
    int which = t >> 14;
    int i = t & 16383;
    int n = i & 127, k = i >> 7;
    const float* W = which == 0 ? Wa : which == 1 ? Wb : Wc;
    short* Wt = which == 0 ? Wta : which == 1 ? Wtb : Wtc;
    Wt[n * 128 + k] = (short)f2bf_bits(W[k * 128 + n]);
}

// -------- GEMM1: H(bf16) = relu(X @ W_in + b_in) --------------------------
// Weights register-resident per wave (wave w owns cols [32w,32w+32), 2
// n-tiles); X tile staged fp32->bf16 into LDS (stride 272B); MFMA reads
// frags via ds_read_b128. Same accumulation order as round 6 -> bit-identical.
__global__ __launch_bounds__(256) void k_gemm_in(const float* __restrict__ X,
                                                 const short* __restrict__ Wt,
                                                 const float* __restrict__ b,
                                                 unsigned short* __restrict__ H) {
    __shared__ unsigned short lds[64 * LROW];
    int tid = threadIdx.x;
    int lane = tid & 63, wv = tid >> 6;
    int quad = lane >> 4, c16 = lane & 15;

    bf16x8 wf[2][4];
    float bb[2];
#pragma unroll
    for (int nt = 0; nt < 2; nt++) {
        int ng = wv * 2 + nt;
        bb[nt] = b[ng * 16 + c16];
#pragma unroll
        for (int kc = 0; kc < 4; kc++)
            wf[nt][kc] = *(const bf16x8*)&Wt[(ng * 16 + c16) * 128 + kc * 32 + quad * 8];
    }

    int tilebase = blockIdx.x * 64;
    const float4* Xg = (const float4*)X;
#pragma unroll
    for (int i = 0; i < 4; i++) {
        int c = tid + i * 256;           // 1024 chunks: row=c>>4, 8-float group o=c&15
        int r = c >> 4, o = c & 15;
        int grow = tilebase + r;
        float4 f0 = make_float4(0.f, 0.f, 0.f, 0.f), f1 = f0;
        if (grow < N_NODES) {
            f0 = Xg[(size_t)grow * 32 + o * 2];
            f1 = Xg[(size_t)grow * 32 + o * 2 + 1];
        }
        *(bf16x8*)&lds[r * LROW + o * 8] = pack_bf8(f0, f1);
    }
    __syncthreads();

    f32x4 acc[4][2] = {};
#pragma unroll
    for (int t4 = 0; t4 < 4; t4++) {
#pragma unroll
        for (int kc = 0; kc < 4; kc++) {
            bf16x8 af = *(const bf16x8*)&lds[(t4 * 16 + c16) * LROW + kc * 32 + quad * 8];
#pragma unroll
            for (int nt = 0; nt < 2; nt++)
                acc[t4][nt] = __builtin_amdgcn_mfma_f32_16x16x32_bf16(af, wf[nt][kc],
                                                                     acc[t4][nt], 0, 0, 0);
        }
    }
    __syncthreads();  // all frag reads done; reuse lds for output tile

#pragma unroll
    for (int t4 = 0; t4 < 4; t4++)
#pragma unroll
        for (int nt = 0; nt < 2; nt++) {
            int ncol = (wv * 2 + nt) * 16 + c16;
#pragma unroll
            for (int r = 0; r < 4; r++) {
                float v = fmaxf(acc[t4][nt][r] + bb[nt], 0.f);
                lds[(t4 * 16 + quad * 4 + r) * LROW + ncol] = (unsigned short)f2bf_bits(v);
            }
        }
    __syncthreads();
#pragma unroll
    for (int i = 0; i < 4; i++) {
        int c = tid + i * 256;
        int r = c >> 4, o = c & 15;
        int grow = tilebase + r;
        if (grow < N_NODES)
            *(uint4*)&H[(size_t)grow * 128 + o * 8] = *(const uint4*)&lds[r * LROW + o * 8];
    }
}

// ------- SpMM: wave per row, QUARTER-WAVE per edge (4 edges/gather instr) ---
__global__ __launch_bounds__(256) void k_spmm(const int* __restrict__ rp,
                                              const unsigned* __restrict__ evf,
                                              const unsigned* __restrict__ Hin,
                                              unsigned* __restrict__ Ho) {
    int wid = (blockIdx.x * blockDim.x + threadIdx.x) >> 6;
    int lane = threadIdx.x & 63;
    if (wid >= N_NODES) return;
    int q = lane >> 4, l16 = lane & 15;
    int s = __builtin_amdgcn_readfirstlane(rp[wid]);
    int e = __builtin_amdgcn_readfirstlane(rp[wid + 1]);
    float a0 = 0.f, a1 = 0.f, a2 = 0.f, a3 = 0.f;
    float a4 = 0.f, a5 = 0.f, a6 = 0.f, a7 = 0.f;
    int j = s;
    for (; j + 8 <= e; j += 8) {
        unsigned ua = evf[j + q];
        unsigned ub = evf[j + 4 + q];
        const uint4 ha = *(const uint4*)&Hin[(size_t)(ua >> 15) * 64 + l16 * 4];
        const uint4 hb = *(const uint4*)&Hin[(size_t)(ub >> 15) * 64 + l16 * 4];
        float va = (float)(ua & 32767u);
        float vb = (float)(ub & 32767u);
        a0 += va * bf_lo(ha.x) + vb * bf_lo(hb.x);
        a1 += va * bf_hi(ha.x) + vb * bf_hi(hb.x);
        a2 += va * bf_lo(ha.y) + vb * bf_lo(hb.y);
        a3 += va * bf_hi(ha.y) + vb * bf_hi(hb.y);
        a4 += va * bf_lo(ha.z) + vb * bf_lo(hb.z);
        a5 += va * bf_hi(ha.z) + vb * bf_hi(hb.z);
        a6 += va * bf_lo(ha.w) + vb * bf_lo(hb.w);
        a7 += va * bf_hi(ha.w) + vb * bf_hi(hb.w);
    }
    for (; j < e; j += 4) {
        int idx = j + q;
        unsigned ua = evf[idx < e ? idx : e - 1];
        const uint4 ha = *(const uint4*)&Hin[(size_t)(ua >> 15) * 64 + l16 * 4];
        float va = (idx < e) ? (float)(ua & 32767u) : 0.f;
        a0 += va * bf_lo(ha.x);
        a1 += va * bf_hi(ha.x);
        a2 += va * bf_lo(ha.y);
        a3 += va * bf_hi(ha.y);
        a4 += va * bf_lo(ha.z);
        a5 += va * bf_hi(ha.z);
        a6 += va * bf_lo(ha.w);
        a7 += va * bf_hi(ha.w);
    }
    a0 += __shfl_xor(a0, 16, 64); a0 += __shfl_xor(a0, 32, 64);
    a1 += __shfl_xor(a1, 16, 64); a1 += __shfl_xor(a1, 32, 64);
    a2 += __shfl_xor(a2, 16, 64); a2 += __shfl_xor(a2, 32, 64);
    a3 += __shfl_xor(a3, 16, 64); a3 += __shfl_xor(a3, 32, 64);
    a4 += __shfl_xor(a4, 16, 64); a4 += __shfl_xor(a4, 32, 64);
    a5 += __shfl_xor(a5, 16, 64); a5 += __shfl_xor(a5, 32, 64);
    a6 += __shfl_xor(a6, 16, 64); a6 += __shfl_xor(a6, 32, 64);
    a7 += __shfl_xor(a7, 16, 64); a7 += __shfl_xor(a7, 32, 64);
    if (q == 0) {
        const float sc = 1.f / 32768.f;
        uint4 p;
        p.x = (f2bf_bits(a1 * sc) << 16) | f2bf_bits(a0 * sc);
        p.y = (f2bf_bits(a3 * sc) << 16) | f2bf_bits(a2 * sc);
        p.z = (f2bf_bits(a5 * sc) << 16) | f2bf_bits(a4 * sc);
        p.w = (f2bf_bits(a7 * sc) << 16) | f2bf_bits(a6 * sc);
        *(uint4*)&Ho[(size_t)wid * 64 + l16 * 4] = p;
    }
}

// ------- Final: out = relu(AH@W1 + A2H@W2) @ W_out + b_out ------------------
// Weights (both matrices) register-resident per wave; AH/A2H tiles staged
// into LDS; cross-wave column reduction through LDS part[].
__global__ __launch_bounds__(256) void k_gemm_out(const unsigned short* __restrict__ AH,
                                                  const unsigned short* __restrict__ A2H,
                                                  const short* __restrict__ Wt1,
                                                  const short* __restrict__ Wt2,
                                                  const float* __restrict__ Wout,
                                                  const float* __restrict__ bout,
                                                  float* __restrict__ out) {
    __shared__ unsigned short lds[2][64 * LROW];
    __shared__ float part[4][64];
    int tid = threadIdx.x;
    int lane = tid & 63, wv = tid >> 6;
    int quad = lane >> 4, c16 = lane & 15;

    bf16x8 w1f[2][4], w2f[2][4];
    float wo[2];
#pragma unroll
    for (int nt = 0; nt < 2; nt++) {
        int ng = wv * 2 + nt;
        wo[nt] = Wout[ng * 16 + c16];
#pragma unroll
        for (int kc = 0; kc < 4; kc++) {
            w1f[nt][kc] = *(const bf16x8*)&Wt1[(ng * 16 + c16) * 128 + kc * 32 + quad * 8];
            w2f[nt][kc] = *(const bf16x8*)&Wt2[(ng * 16 + c16) * 128 + kc * 32 + quad * 8];
        }
    }
    float bo = bout[0];

    int tilebase = blockIdx.x * 64;
    const uint4* Ag = (const uint4*)(AH + (size_t)tilebase * 128);
    const uint4* Bg = (const uint4*)(A2H + (size_t)tilebase * 128);
#pragma unroll
    for (int i = 0; i < 4; i++) {
        int c = tid + i * 256;
        int r = c >> 4, o = c & 15;
        *(uint4*)&lds[0][r * LROW + o * 8] = Ag[c];  // reads past N stay in ws: safe
        *(uint4*)&lds[1][r * LROW + o * 8] = Bg[c];
    }
    __syncthreads();

    f32x4 acc[4][2] = {};
#pragma unroll
    for (int t4 = 0; t4 < 4; t4++) {
#pragma unroll
        for (int kc = 0; kc < 4; kc++) {
            bf16x8 afA = *(const bf16x8*)&lds[0][(t4 * 16 + c16) * LROW + kc * 32 + quad * 8];
            bf16x8 afB = *(const bf16x8*)&lds[1][(t4 * 16 + c16) * LROW + kc * 32 + quad * 8];
#pragma unroll
            for (int nt = 0; nt < 2; nt++) {
                acc[t4][nt] = __builtin_amdgcn_mfma_f32_16x16x32_bf16(afA, w1f[nt][kc],
                                                                     acc[t4][nt], 0, 0, 0);
                acc[t4][nt] = __builtin_amdgcn_mfma_f32_16x16x32_bf16(afB, w2f[nt][kc],
                                                                     acc[t4][nt], 0, 0, 0);
            }
        }
    }

#pragma unroll
    for (int t4 = 0; t4 < 4; t4++) {
        float p[4];
#pragma unroll
        for (int r = 0; r < 4; r++)
            p[r] = fmaxf(acc[t4][0][r], 0.f) * wo[0] + fmaxf(acc[t4][1][r], 0.f) * wo[1];
#pragma unroll
        for (int m = 1; m < 16; m <<= 1)
#pragma unroll
            for (int r = 0; r < 4; r++) p[r] += __shfl_xor(p[r], m, 64);
        if (c16 == 0)
#pragma unroll
            for (int r = 0; r < 4; r++) part[wv][t4 * 16 + quad * 4 + r] = p[r];
    }
    __syncthreads();
    if (tid < 64) {
        int orow = tilebase + tid;
        if (orow < N_NODES)
            out[orow] = part[0][tid] + part[1][tid] + part[2][tid] + part[3][tid] + bo;
    }
}

// ---------------- launch ----------------

extern "C" void kernel_launch(void* const* d_in, const int* in_sizes, int n_in,
                              void* d_out, int out_size, void* d_ws, size_t ws_size,
                              hipStream_t stream) {
    const float* X    = (const float*)d_in[0];
    const int*   row  = (const int*)d_in[1];
    const int*   col  = (const int*)d_in[2];
    const float* vals = (const float*)d_in[3];
    const float* W_in = (const float*)d_in[4];
    const float* b_in = (const float*)d_in[5];
    const float* W1   = (const float*)d_in[6];
    const float* W2   = (const float*)d_in[7];
    const float* Wout = (const float*)d_in[8];
    const float* bout = (const float*)d_in[9];
    float* out = (float*)d_out;

    char* ws = (char*)d_ws;
    size_t off = 0;
    auto alloc = [&](size_t bytes) -> void* {
        void* p = ws + off;
        off += (bytes + 511) & ~(size_t)511;
        return p;
    };
    unsigned short* Hb  = (unsigned short*)alloc((size_t)N_NODES * 128 * 2);  // H bf16
    unsigned short* AHb = (unsigned short*)alloc((size_t)N_NODES * 128 * 2);  // AH bf16
    unsigned short* A2b = (unsigned short*)alloc((size_t)N_NODES * 128 * 2);  // A2H bf16
    unsigned* evf  = (unsigned*)alloc((size_t)N_EDGES * 4);
    int2* grouped  = (int2*)alloc((size_t)N_EDGES * 8);
    short* Wtin    = (short*)alloc(128 * 128 * 2);
    short* Wt1     = (short*)alloc(128 * 128 * 2);
    short* Wt2     = (short*)alloc(128 * 128 * 2);
    int*   hmat    = (int*)alloc((size_t)NCHUNK * NBUCK * 4);
    int*   bases   = (int*)alloc((size_t)NCHUNK * NBUCK * 4);
    int*   bcnt    = (int*)alloc(512 * 4);
    int*   bstart  = (int*)alloc(512 * 4);
    int*   row_ptr = (int*)alloc((size_t)(N_NODES + 256) * 4);

    k_binA<<<NCHUNK, 256, 0, stream>>>(row, hmat);
    k_colscan<<<NBUCK, 256, 0, stream>>>(hmat, bases, bcnt);
    k_scanB<<<1, 512, 0, stream>>>(bcnt, bstart);
    k_binC<<<NCHUNK, 256, 0, stream>>>(row, col, vals, bstart, bases, grouped);
    k_binD<<<NBUCK, 256, 0, stream>>>(grouped, bstart, evf, row_ptr);

    k_cvtw3<<<192, 256, 0, stream>>>(W_in, W1, W2, Wtin, Wt1, Wt2);

    int gblk = (N_NODES + 63) / 64;  // 1563
    k_gemm_in<<<gblk, 256, 0, stream>>>(X, Wtin, b_in, Hb);

    int sblk = (N_NODES + 3) / 4;  // 4 waves/block, 1 row/wave
    k_spmm<<<sblk, 256, 0, stream>>>(row_ptr, evf, (const unsigned*)Hb, (unsigned*)AHb);
    k_spmm<<<sblk, 256, 0, stream>>>(row_ptr, evf, (const unsigned*)AHb, (unsigned*)A2b);

    k_gemm_out<<<gblk, 256, 0, stream>>>(AHb, A2b, Wt1, Wt2, Wout, bout, out);
}

// Round 8
// 305.848 us; speedup vs baseline: 8.2396x; 1.0294x over previous
//
#include <hip/hip_runtime.h>

#define N_NODES 100000
#define N_EDGES 1600000
#define NBUCK 391   // ceil(N_NODES / 256) buckets of 256 rows
#define NCHUNK 256  // blocks in passes A/C
#define CHUNK 6250  // N_EDGES / NCHUNK exactly
#define LROW 136    // LDS row stride in shorts (272B): optimal bank pattern
#define DCAP 5120   // binD LDS edge capacity (40KB); Poisson(4096) max ~4400

typedef float f32x4 __attribute__((ext_vector_type(4)));
typedef short bf16x8 __attribute__((ext_vector_type(8)));

// fp32 -> bf16 round-to-nearest-even, bits in low 16.
__device__ __forceinline__ unsigned f2bf_bits(float f) {
    unsigned u = __float_as_uint(f);
    u += 0x7fffu + ((u >> 16) & 1u);
    return u >> 16;
}
__device__ __forceinline__ float bf_lo(unsigned u) { return __uint_as_float(u << 16); }
__device__ __forceinline__ float bf_hi(unsigned u) { return __uint_as_float(u & 0xffff0000u); }

__device__ __forceinline__ bf16x8 pack_bf8(float4 a, float4 b) {
    bf16x8 r;
    r[0] = (short)f2bf_bits(a.x); r[1] = (short)f2bf_bits(a.y);
    r[2] = (short)f2bf_bits(a.z); r[3] = (short)f2bf_bits(a.w);
    r[4] = (short)f2bf_bits(b.x); r[5] = (short)f2bf_bits(b.y);
    r[6] = (short)f2bf_bits(b.z); r[7] = (short)f2bf_bits(b.w);
    return r;
}

// ============ CSR build: bucket binning, zero contended global atomics ======

__global__ __launch_bounds__(256) void k_binA(const int* __restrict__ row,
                                              int* __restrict__ hmat) {
    __shared__ int h[NBUCK];
    for (int i = threadIdx.x; i < NBUCK; i += 256) h[i] = 0;
    __syncthreads();
    int s = blockIdx.x * CHUNK, e = s + CHUNK;
    for (int i = s + threadIdx.x; i < e; i += 256)
        atomicAdd(&h[row[i] >> 8], 1);
    __syncthreads();
    for (int b = threadIdx.x; b < NBUCK; b += 256)
        hmat[blockIdx.x * NBUCK + b] = h[b];
}

__global__ __launch_bounds__(256) void k_colscan(const int* __restrict__ hmat,
                                                 int* __restrict__ bases,
                                                 int* __restrict__ bcnt) {
    __shared__ int s[256];
    int b = blockIdx.x, t = threadIdx.x;
    int v = hmat[t * NBUCK + b];
    s[t] = v;
    __syncthreads();
    for (int off = 1; off < 256; off <<= 1) {
        int x = (t >= off) ? s[t - off] : 0;
        __syncthreads();
        s[t] += x;
        __syncthreads();
    }
    bases[t * NBUCK + b] = s[t] - v;
    if (t == 255) bcnt[b] = s[255];
}

__global__ void k_scanB(const int* __restrict__ bcnt, int* __restrict__ bstart) {
    __shared__ int s[512];
    int t = threadIdx.x;
    int v = (t < NBUCK) ? bcnt[t] : 0;
    s[t] = v;
    __syncthreads();
    for (int off = 1; off < 512; off <<= 1) {
        int x = (t >= off) ? s[t - off] : 0;
        __syncthreads();
        s[t] += x;
        __syncthreads();
    }
    if (t < NBUCK) bstart[t] = s[t] - v;
    if (t == NBUCK) bstart[NBUCK] = N_EDGES;
}

__global__ __launch_bounds__(256) void k_binC(const int* __restrict__ row,
                                              const int* __restrict__ col,
                                              const float* __restrict__ vals,
                                              const int* __restrict__ bstart,
                                              const int* __restrict__ bases,
                                              int2* __restrict__ grouped) {
    __shared__ int cnt[NBUCK];
    for (int i = threadIdx.x; i < NBUCK; i += 256) cnt[i] = 0;
    __syncthreads();
    int s = blockIdx.x * CHUNK, e = s + CHUNK;
    for (int i = s + threadIdx.x; i < e; i += 256) {
        int r = row[i];
        int b = r >> 8;
        int rank = atomicAdd(&cnt[b], 1);
        int pos = bstart[b] + bases[blockIdx.x * NBUCK + b] + rank;
        int q = __float2int_rn(vals[i] * 32768.f);
        if (q > 32767) q = 32767;
        grouped[pos] = make_int2(col[i], ((r & 255) << 15) | q);
    }
}

// Pass D: one block per bucket; bucket's edges staged once into LDS (avg
// 32KB), histogram+scan -> row_ptr, rank-scatter into final CSR order.
// Global-path fallback if a bucket ever exceeds DCAP.
__global__ __launch_bounds__(256) void k_binD(const int2* __restrict__ grouped,
                                              const int* __restrict__ bstart,
                                              unsigned* __restrict__ evf,
                                              int* __restrict__ row_ptr) {
    __shared__ int h[256], sc[256], cur[256];
    __shared__ int2 ebuf[DCAP];
    int b = blockIdx.x, t = threadIdx.x;
    int s0 = bstart[b], e0 = bstart[b + 1];
    int n = e0 - s0;
    bool inlds = (n <= DCAP);  // block-uniform
    h[t] = 0;
    __syncthreads();
    if (inlds) {
        for (int i = t; i < n; i += 256) ebuf[i] = grouped[s0 + i];
        __syncthreads();
        for (int i = t; i < n; i += 256)
            atomicAdd(&h[(ebuf[i].y >> 15) & 255], 1);
    } else {
        for (int i = s0 + t; i < e0; i += 256)
            atomicAdd(&h[(grouped[i].y >> 15) & 255], 1);
    }
    __syncthreads();
    int v = h[t];
    sc[t] = v;
    __syncthreads();
    for (int off = 1; off < 256; off <<= 1) {
        int x = (t >= off) ? sc[t - off] : 0;
        __syncthreads();
        sc[t] += x;
        __syncthreads();
    }
    int excl = sc[t] - v;
    cur[t] = excl;
    int grow = b * 256 + t;
    if (grow <= N_NODES) row_ptr[grow] = s0 + excl;
    __syncthreads();
    if (inlds) {
        for (int i = t; i < n; i += 256) {
            int2 g = ebuf[i];
            int rl = (g.y >> 15) & 255;
            int p = atomicAdd(&cur[rl], 1);
            evf[s0 + p] = ((unsigned)g.x << 15) | (unsigned)(g.y & 32767);
        }
    } else {
        for (int i = s0 + t; i < e0; i += 256) {
            int2 g = grouped[i];
            int rl = (g.y >> 15) & 255;
            int p = atomicAdd(&cur[rl], 1);
            evf[s0 + p] = ((unsigned)g.x << 15) | (unsigned)(g.y & 32767);
        }
    }
}

// ---------------- weight convert+transpose: Wt[n][k] = bf16(W[k][n]) -------
__global__ void k_cvtw3(const float* __restrict__ Wa, const float* __restrict__ Wb,
                        const float* __restrict__ Wc, short* __restrict__ Wta,
                        short* __restrict__ Wtb, short* __restrict__ Wtc) {
    int t = blockIdx.x * 256 + threadIdx.x;
    int which = t >> 14;
    int i = t & 16383;
    int n = i & 127, k = i >> 7;
    const float* W = which == 0 ? Wa : which == 1 ? Wb : Wc;
    short* Wt = which == 0 ? Wta : which == 1 ? Wtb : Wtc;
    Wt[n * 128 + k] = (short)f2bf_bits(W[k * 128 + n]);
}

// -------- GEMM1: H(bf16) = relu(X @ W_in + b_in) --------------------------
__global__ __launch_bounds__(256) void k_gemm_in(const float* __restrict__ X,
                                                 const short* __restrict__ Wt,
                                                 const float* __restrict__ b,
                                                 unsigned short* __restrict__ H) {
    __shared__ unsigned short lds[64 * LROW];
    int tid = threadIdx.x;
    int lane = tid & 63, wv = tid >> 6;
    int quad = lane >> 4, c16 = lane & 15;

    bf16x8 wf[2][4];
    float bb[2];
#pragma unroll
    for (int nt = 0; nt < 2; nt++) {
        int ng = wv * 2 + nt;
        bb[nt] = b[ng * 16 + c16];
#pragma unroll
        for (int kc = 0; kc < 4; kc++)
            wf[nt][kc] = *(const bf16x8*)&Wt[(ng * 16 + c16) * 128 + kc * 32 + quad * 8];
    }

    int tilebase = blockIdx.x * 64;
    const float4* Xg = (const float4*)X;
#pragma unroll
    for (int i = 0; i < 4; i++) {
        int c = tid + i * 256;
        int r = c >> 4, o = c & 15;
        int grow = tilebase + r;
        float4 f0 = make_float4(0.f, 0.f, 0.f, 0.f), f1 = f0;
        if (grow < N_NODES) {
            f0 = Xg[(size_t)grow * 32 + o * 2];
            f1 = Xg[(size_t)grow * 32 + o * 2 + 1];
        }
        *(bf16x8*)&lds[r * LROW + o * 8] = pack_bf8(f0, f1);
    }
    __syncthreads();

    f32x4 acc[4][2] = {};
#pragma unroll
    for (int t4 = 0; t4 < 4; t4++) {
#pragma unroll
        for (int kc = 0; kc < 4; kc++) {
            bf16x8 af = *(const bf16x8*)&lds[(t4 * 16 + c16) * LROW + kc * 32 + quad * 8];
#pragma unroll
            for (int nt = 0; nt < 2; nt++)
                acc[t4][nt] = __builtin_amdgcn_mfma_f32_16x16x32_bf16(af, wf[nt][kc],
                                                                     acc[t4][nt], 0, 0, 0);
        }
    }
    __syncthreads();

#pragma unroll
    for (int t4 = 0; t4 < 4; t4++)
#pragma unroll
        for (int nt = 0; nt < 2; nt++) {
            int ncol = (wv * 2 + nt) * 16 + c16;
#pragma unroll
            for (int r = 0; r < 4; r++) {
                float v = fmaxf(acc[t4][nt][r] + bb[nt], 0.f);
                lds[(t4 * 16 + quad * 4 + r) * LROW + ncol] = (unsigned short)f2bf_bits(v);
            }
        }
    __syncthreads();
#pragma unroll
    for (int i = 0; i < 4; i++) {
        int c = tid + i * 256;
        int r = c >> 4, o = c & 15;
        int grow = tilebase + r;
        if (grow < N_NODES)
            *(uint4*)&H[(size_t)grow * 128 + o * 8] = *(const uint4*)&lds[r * LROW + o * 8];
    }
}

// ------- SpMM: wave per row, quarter-wave per edge, 16 edges per round ------
// One round issues 4 independent 1KB gathers (16 edges) before any FMA:
// typical row (deg~16) pays gather latency once. Tail = masked/clamped round.
__global__ __launch_bounds__(256) void k_spmm(const int* __restrict__ rp,
                                              const unsigned* __restrict__ evf,
                                              const unsigned* __restrict__ Hin,
                                              unsigned* __restrict__ Ho) {
    int wid = (blockIdx.x * blockDim.x + threadIdx.x) >> 6;
    int lane = threadIdx.x & 63;
    if (wid >= N_NODES) return;
    int q = lane >> 4, l16 = lane & 15;
    int s = __builtin_amdgcn_readfirstlane(rp[wid]);
    int e = __builtin_amdgcn_readfirstlane(rp[wid + 1]);
    float a0 = 0.f, a1 = 0.f, a2 = 0.f, a3 = 0.f;
    float a4 = 0.f, a5 = 0.f, a6 = 0.f, a7 = 0.f;
    int j = s;
    for (; j + 16 <= e; j += 16) {
        unsigned u0 = evf[j + q];
        unsigned u1 = evf[j + 4 + q];
        unsigned u2 = evf[j + 8 + q];
        unsigned u3 = evf[j + 12 + q];
        const uint4 h0 = *(const uint4*)&Hin[(size_t)(u0 >> 15) * 64 + l16 * 4];
        const uint4 h1 = *(const uint4*)&Hin[(size_t)(u1 >> 15) * 64 + l16 * 4];
        const uint4 h2 = *(const uint4*)&Hin[(size_t)(u2 >> 15) * 64 + l16 * 4];
        const uint4 h3 = *(const uint4*)&Hin[(size_t)(u3 >> 15) * 64 + l16 * 4];
        float v0 = (float)(u0 & 32767u);
        float v1 = (float)(u1 & 32767u);
        float v2 = (float)(u2 & 32767u);
        float v3 = (float)(u3 & 32767u);
        a0 += v0 * bf_lo(h0.x) + v1 * bf_lo(h1.x) + v2 * bf_lo(h2.x) + v3 * bf_lo(h3.x);
        a1 += v0 * bf_hi(h0.x) + v1 * bf_hi(h1.x) + v2 * bf_hi(h2.x) + v3 * bf_hi(h3.x);
        a2 += v0 * bf_lo(h0.y) + v1 * bf_lo(h1.y) + v2 * bf_lo(h2.y) + v3 * bf_lo(h3.y);
        a3 += v0 * bf_hi(h0.y) + v1 * bf_hi(h1.y) + v2 * bf_hi(h2.y) + v3 * bf_hi(h3.y);
        a4 += v0 * bf_lo(h0.z) + v1 * bf_lo(h1.z) + v2 * bf_lo(h2.z) + v3 * bf_lo(h3.z);
        a5 += v0 * bf_hi(h0.z) + v1 * bf_hi(h1.z) + v2 * bf_hi(h2.z) + v3 * bf_hi(h3.z);
        a6 += v0 * bf_lo(h0.w) + v1 * bf_lo(h1.w) + v2 * bf_lo(h2.w) + v3 * bf_lo(h3.w);
        a7 += v0 * bf_hi(h0.w) + v1 * bf_hi(h1.w) + v2 * bf_hi(h2.w) + v3 * bf_hi(h3.w);
    }
    if (j < e) {
        int i0 = j + q, i1 = j + 4 + q, i2 = j + 8 + q, i3 = j + 12 + q;
        unsigned u0 = evf[i0 < e ? i0 : e - 1];
        unsigned u1 = evf[i1 < e ? i1 : e - 1];
        unsigned u2 = evf[i2 < e ? i2 : e - 1];
        unsigned u3 = evf[i3 < e ? i3 : e - 1];
        const uint4 h0 = *(const uint4*)&Hin[(size_t)(u0 >> 15) * 64 + l16 * 4];
        const uint4 h1 = *(const uint4*)&Hin[(size_t)(u1 >> 15) * 64 + l16 * 4];
        const uint4 h2 = *(const uint4*)&Hin[(size_t)(u2 >> 15) * 64 + l16 * 4];
        const uint4 h3 = *(const uint4*)&Hin[(size_t)(u3 >> 15) * 64 + l16 * 4];
        float v0 = (i0 < e) ? (float)(u0 & 32767u) : 0.f;
        float v1 = (i1 < e) ? (float)(u1 & 32767u) : 0.f;
        float v2 = (i2 < e) ? (float)(u2 & 32767u) : 0.f;
        float v3 = (i3 < e) ? (float)(u3 & 32767u) : 0.f;
        a0 += v0 * bf_lo(h0.x) + v1 * bf_lo(h1.x) + v2 * bf_lo(h2.x) + v3 * bf_lo(h3.x);
        a1 += v0 * bf_hi(h0.x) + v1 * bf_hi(h1.x) + v2 * bf_hi(h2.x) + v3 * bf_hi(h3.x);
        a2 += v0 * bf_lo(h0.y) + v1 * bf_lo(h1.y) + v2 * bf_lo(h2.y) + v3 * bf_lo(h3.y);
        a3 += v0 * bf_hi(h0.y) + v1 * bf_hi(h1.y) + v2 * bf_hi(h2.y) + v3 * bf_hi(h3.y);
        a4 += v0 * bf_lo(h0.z) + v1 * bf_lo(h1.z) + v2 * bf_lo(h2.z) + v3 * bf_lo(h3.z);
        a5 += v0 * bf_hi(h0.z) + v1 * bf_hi(h1.z) + v2 * bf_hi(h2.z) + v3 * bf_hi(h3.z);
        a6 += v0 * bf_lo(h0.w) + v1 * bf_lo(h1.w) + v2 * bf_lo(h2.w) + v3 * bf_lo(h3.w);
        a7 += v0 * bf_hi(h0.w) + v1 * bf_hi(h1.w) + v2 * bf_hi(h2.w) + v3 * bf_hi(h3.w);
    }
    a0 += __shfl_xor(a0, 16, 64); a0 += __shfl_xor(a0, 32, 64);
    a1 += __shfl_xor(a1, 16, 64); a1 += __shfl_xor(a1, 32, 64);
    a2 += __shfl_xor(a2, 16, 64); a2 += __shfl_xor(a2, 32, 64);
    a3 += __shfl_xor(a3, 16, 64); a3 += __shfl_xor(a3, 32, 64);
    a4 += __shfl_xor(a4, 16, 64); a4 += __shfl_xor(a4, 32, 64);
    a5 += __shfl_xor(a5, 16, 64); a5 += __shfl_xor(a5, 32, 64);
    a6 += __shfl_xor(a6, 16, 64); a6 += __shfl_xor(a6, 32, 64);
    a7 += __shfl_xor(a7, 16, 64); a7 += __shfl_xor(a7, 32, 64);
    if (q == 0) {
        const float sc = 1.f / 32768.f;
        uint4 p;
        p.x = (f2bf_bits(a1 * sc) << 16) | f2bf_bits(a0 * sc);
        p.y = (f2bf_bits(a3 * sc) << 16) | f2bf_bits(a2 * sc);
        p.z = (f2bf_bits(a5 * sc) << 16) | f2bf_bits(a4 * sc);
        p.w = (f2bf_bits(a7 * sc) << 16) | f2bf_bits(a6 * sc);
        *(uint4*)&Ho[(size_t)wid * 64 + l16 * 4] = p;
    }
}

// ------- Final: out = relu(AH@W1 + A2H@W2) @ W_out + b_out ------------------
__global__ __launch_bounds__(256) void k_gemm_out(const unsigned short* __restrict__ AH,
                                                  const unsigned short* __restrict__ A2H,
                                                  const short* __restrict__ Wt1,
                                                  const short* __restrict__ Wt2,
                                                  const float* __restrict__ Wout,
                                                  const float* __restrict__ bout,
                                                  float* __restrict__ out) {
    __shared__ unsigned short lds[2][64 * LROW];
    __shared__ float part[4][64];
    int tid = threadIdx.x;
    int lane = tid & 63, wv = tid >> 6;
    int quad = lane >> 4, c16 = lane & 15;

    bf16x8 w1f[2][4], w2f[2][4];
    float wo[2];
#pragma unroll
    for (int nt = 0; nt < 2; nt++) {
        int ng = wv * 2 + nt;
        wo[nt] = Wout[ng * 16 + c16];
#pragma unroll
        for (int kc = 0; kc < 4; kc++) {
            w1f[nt][kc] = *(const bf16x8*)&Wt1[(ng * 16 + c16) * 128 + kc * 32 + quad * 8];
            w2f[nt][kc] = *(const bf16x8*)&Wt2[(ng * 16 + c16) * 128 + kc * 32 + quad * 8];
        }
    }
    float bo = bout[0];

    int tilebase = blockIdx.x * 64;
    const uint4* Ag = (const uint4*)(AH + (size_t)tilebase * 128);
    const uint4* Bg = (const uint4*)(A2H + (size_t)tilebase * 128);
#pragma unroll
    for (int i = 0; i < 4; i++) {
        int c = tid + i * 256;
        int r = c >> 4, o = c & 15;
        *(uint4*)&lds[0][r * LROW + o * 8] = Ag[c];
        *(uint4*)&lds[1][r * LROW + o * 8] = Bg[c];
    }
    __syncthreads();

    f32x4 acc[4][2] = {};
#pragma unroll
    for (int t4 = 0; t4 < 4; t4++) {
#pragma unroll
        for (int kc = 0; kc < 4; kc++) {
            bf16x8 afA = *(const bf16x8*)&lds[0][(t4 * 16 + c16) * LROW + kc * 32 + quad * 8];
            bf16x8 afB = *(const bf16x8*)&lds[1][(t4 * 16 + c16) * LROW + kc * 32 + quad * 8];
#pragma unroll
            for (int nt = 0; nt < 2; nt++) {
                acc[t4][nt] = __builtin_amdgcn_mfma_f32_16x16x32_bf16(afA, w1f[nt][kc],
                                                                     acc[t4][nt], 0, 0, 0);
                acc[t4][nt] = __builtin_amdgcn_mfma_f32_16x16x32_bf16(afB, w2f[nt][kc],
                                                                     acc[t4][nt], 0, 0, 0);
            }
        }
    }

#pragma unroll
    for (int t4 = 0; t4 < 4; t4++) {
        float p[4];
#pragma unroll
        for (int r = 0; r < 4; r++)
            p[r] = fmaxf(acc[t4][0][r], 0.f) * wo[0] + fmaxf(acc[t4][1][r], 0.f) * wo[1];
#pragma unroll
        for (int m = 1; m < 16; m <<= 1)
#pragma unroll
            for (int r = 0; r < 4; r++) p[r] += __shfl_xor(p[r], m, 64);
        if (c16 == 0)
#pragma unroll
            for (int r = 0; r < 4; r++) part[wv][t4 * 16 + quad * 4 + r] = p[r];
    }
    __syncthreads();
    if (tid < 64) {
        int orow = tilebase + tid;
        if (orow < N_NODES)
            out[orow] = part[0][tid] + part[1][tid] + part[2][tid] + part[3][tid] + bo;
    }
}

// ---------------- launch ----------------

extern "C" void kernel_launch(void* const* d_in, const int* in_sizes, int n_in,
                              void* d_out, int out_size, void* d_ws, size_t ws_size,
                              hipStream_t stream) {
    const float* X    = (const float*)d_in[0];
    const int*   row  = (const int*)d_in[1];
    const int*   col  = (const int*)d_in[2];
    const float* vals = (const float*)d_in[3];
    const float* W_in = (const float*)d_in[4];
    const float* b_in = (const float*)d_in[5];
    const float* W1   = (const float*)d_in[6];
    const float* W2   = (const float*)d_in[7];
    const float* Wout = (const float*)d_in[8];
    const float* bout = (const float*)d_in[9];
    float* out = (float*)d_out;

    char* ws = (char*)d_ws;
    size_t off = 0;
    auto alloc = [&](size_t bytes) -> void* {
        void* p = ws + off;
        off += (bytes + 511) & ~(size_t)511;
        return p;
    };
    unsigned short* Hb  = (unsigned short*)alloc((size_t)N_NODES * 128 * 2);  // H bf16
    unsigned short* AHb = (unsigned short*)alloc((size_t)N_NODES * 128 * 2);  // AH bf16
    unsigned short* A2b = (unsigned short*)alloc((size_t)N_NODES * 128 * 2);  // A2H bf16
    unsigned* evf  = (unsigned*)alloc((size_t)N_EDGES * 4);
    int2* grouped  = (int2*)alloc((size_t)N_EDGES * 8);
    short* Wtin    = (short*)alloc(128 * 128 * 2);
    short* Wt1     = (short*)alloc(128 * 128 * 2);
    short* Wt2     = (short*)alloc(128 * 128 * 2);
    int*   hmat    = (int*)alloc((size_t)NCHUNK * NBUCK * 4);
    int*   bases   = (int*)alloc((size_t)NCHUNK * NBUCK * 4);
    int*   bcnt    = (int*)alloc(512 * 4);
    int*   bstart  = (int*)alloc(512 * 4);
    int*   row_ptr = (int*)alloc((size_t)(N_NODES + 256) * 4);

    k_binA<<<NCHUNK, 256, 0, stream>>>(row, hmat);
    k_colscan<<<NBUCK, 256, 0, stream>>>(hmat, bases, bcnt);
    k_scanB<<<1, 512, 0, stream>>>(bcnt, bstart);
    k_binC<<<NCHUNK, 256, 0, stream>>>(row, col, vals, bstart, bases, grouped);
    k_binD<<<NBUCK, 256, 0, stream>>>(grouped, bstart, evf, row_ptr);

    k_cvtw3<<<192, 256, 0, stream>>>(W_in, W1, W2, Wtin, Wt1, Wt2);

    int gblk = (N_NODES + 63) / 64;  // 1563
    k_gemm_in<<<gblk, 256, 0, stream>>>(X, Wtin, b_in, Hb);

    int sblk = (N_NODES + 3) / 4;  // 4 waves/block, 1 row/wave
    k_spmm<<<sblk, 256, 0, stream>>>(row_ptr, evf, (const unsigned*)Hb, (unsigned*)AHb);
    k_spmm<<<sblk, 256, 0, stream>>>(row_ptr, evf, (const unsigned*)AHb, (unsigned*)A2b);

    k_gemm_out<<<gblk, 256, 0, stream>>>(AHb, A2b, Wt1, Wt2, Wout, bout, out);
}